// Round 1
// baseline (580.361 us; speedup 1.0000x reference)
//
#include <hip/hip_runtime.h>
#include <stdint.h>

typedef __bf16 bf16_t;
typedef __bf16 bf16x8 __attribute__((ext_vector_type(8)));
typedef __bf16 bf16x4 __attribute__((ext_vector_type(4)));
typedef float f32x4 __attribute__((ext_vector_type(4)));

#define NPT 2048
#define NB  32768

__device__ __forceinline__ float relu_(float v) { return v > 0.f ? v : 0.f; }

// ---------------------------------------------------------------- prep
// params layout (floats):
// 0 bn1_scale[128] |128 bn1_shift[128] |256 bn2_scale[16] |272 bn2_shift[16]
// 288 sa_scale[64] |352 sa_shift[64] |416 fuse_scale[128] |544 fuse_shift[128]
// 672 bns1_scale[512] |1184 bns1_shift[512] |1696 bns2_scale[256] |1952 bns2_shift[256]
__global__ __launch_bounds__(256) void k_prep(
    const float* __restrict__ convs1_w, const float* __restrict__ convs2_w,
    const float* __restrict__ bn1, const float* __restrict__ bn2,
    const float* __restrict__ sa_bn, const float* __restrict__ sa_trans_b,
    const float* __restrict__ fuse_bn, const float* __restrict__ convs1_b,
    const float* __restrict__ bns1, const float* __restrict__ convs2_b,
    const float* __restrict__ bns2,
    bf16_t* __restrict__ wbuf1, bf16_t* __restrict__ wbuf2, float* __restrict__ params)
{
  int idx = blockIdx.x * 256 + threadIdx.x;
  for (int it = 0; it < 5; ++it) {
    int i = idx + it * 65536;
    if (i < 147456) {                       // wbuf1 [512][288], K padded 264->288
      int o = i / 288, c = i - o * 288;
      wbuf1[i] = (bf16_t)(c < 264 ? convs1_w[o * 264 + c] : 0.f);
    } else if (i < 147456 + 131072) {       // wbuf2 [256][512]
      int j = i - 147456;
      wbuf2[j] = (bf16_t)convs2_w[j];
    }
  }
  if (blockIdx.x == 0) {
    for (int t = threadIdx.x; t < 1104; t += 256) {
      float g, be, m, v, extra = 0.f; int so, ho;
      if (t < 128)      { g=bn1[t]; be=bn1[128+t]; m=bn1[256+t]; v=bn1[384+t]; so=t; ho=128+t; }
      else if (t < 144) { int u=t-128; g=bn2[u]; be=bn2[16+u]; m=bn2[32+u]; v=bn2[48+u]; so=256+u; ho=272+u; }
      else if (t < 208) { int u=t-144; int L=u>>4, o=u&15; const float* p=sa_bn+L*64;
                          g=p[o]; be=p[16+o]; m=p[32+o]; v=p[48+o];
                          extra=sa_trans_b[L*16+o]; so=288+u; ho=352+u; }
      else if (t < 336) { int u=t-208; g=fuse_bn[u]; be=fuse_bn[128+u]; m=fuse_bn[256+u]; v=fuse_bn[384+u]; so=416+u; ho=544+u; }
      else if (t < 848) { int u=t-336; g=bns1[u]; be=bns1[512+u]; m=bns1[1024+u]; v=bns1[1536+u]; extra=convs1_b[u]; so=672+u; ho=1184+u; }
      else              { int u=t-848; g=bns2[u]; be=bns2[256+u]; m=bns2[512+u]; v=bns2[768+u]; extra=convs2_b[u]; so=1696+u; ho=1952+u; }
      float sc = g * rsqrtf(v + 1e-5f);
      params[so] = sc;
      params[ho] = (extra - m) * sc + be;
    }
  }
}

// ---------------------------------------------------------------- conv1 (16->128) + bn + relu
__global__ __launch_bounds__(128) void k_conv1(const float* __restrict__ x, const float* __restrict__ w,
                                               const float* __restrict__ params, float* __restrict__ h1)
{
  __shared__ float ws[2048];
  __shared__ float sc[128], sh[128];
  int tid = threadIdx.x;
  for (int i = tid; i < 2048; i += 128) ws[i] = w[i];
  if (tid < 128) { sc[tid] = params[tid]; sh[tid] = params[128 + tid]; }
  __syncthreads();
  int col = blockIdx.x * 128 + tid;
  int b = col >> 11, n = col & 2047;
  const float* xc = x + (size_t)b * 16 * 2048 + n;
  float xr[16];
#pragma unroll
  for (int c = 0; c < 16; ++c) xr[c] = xc[(size_t)c * 2048];
  float* out = h1 + (size_t)b * 128 * 2048 + n;
#pragma unroll 2
  for (int o = 0; o < 128; ++o) {
    float s = 0.f;
#pragma unroll
    for (int c = 0; c < 16; ++c) s = fmaf(ws[o * 16 + c], xr[c], s);
    s = fmaf(s, sc[o], sh[o]);
    out[(size_t)o * 2048] = relu_(s);
  }
}

// ---------------------------------------------------------------- conv2 (128->16) + bn + relu, + layer0 k/v
__global__ __launch_bounds__(128) void k_conv2kv(const float* __restrict__ h1, const float* __restrict__ w2,
    const float* __restrict__ params, const float* __restrict__ qk_w, const float* __restrict__ v_w,
    const float* __restrict__ v_b, float* __restrict__ h0, float* __restrict__ kbuf, float* __restrict__ vbuf)
{
  __shared__ float wsT[2048];   // transposed [c][o]
  __shared__ float sc[16], sh[16], qk[64], vw[256], vb[16];
  int tid = threadIdx.x;
  for (int i = tid; i < 2048; i += 128) { int o = i >> 7, c = i & 127; wsT[c * 16 + o] = w2[i]; }
  for (int i = tid; i < 256; i += 128) vw[i] = v_w[i];
  if (tid < 64) qk[tid] = qk_w[tid];
  if (tid < 16) { sc[tid] = params[256 + tid]; sh[tid] = params[272 + tid]; vb[tid] = v_b[tid]; }
  __syncthreads();
  int col = blockIdx.x * 128 + tid;
  int b = col >> 11, n = col & 2047;
  const float* hc = h1 + (size_t)b * 128 * 2048 + n;
  float acc[16];
#pragma unroll
  for (int o = 0; o < 16; ++o) acc[o] = 0.f;
  for (int c = 0; c < 128; ++c) {
    float hv = hc[(size_t)c * 2048];
    const float* wr = &wsT[c * 16];
#pragma unroll
    for (int o = 0; o < 16; ++o) acc[o] = fmaf(wr[o], hv, acc[o]);
  }
  float hcv[16];
#pragma unroll
  for (int o = 0; o < 16; ++o) {
    float s = fmaf(acc[o], sc[o], sh[o]);
    hcv[o] = relu_(s);
    h0[((size_t)b * 16 + o) * 2048 + n] = hcv[o];
  }
  float s0=0.f,s1=0.f,s2=0.f,s3=0.f;
#pragma unroll
  for (int c = 0; c < 16; ++c) {
    s0 = fmaf(qk[c], hcv[c], s0);  s1 = fmaf(qk[16+c], hcv[c], s1);
    s2 = fmaf(qk[32+c], hcv[c], s2); s3 = fmaf(qk[48+c], hcv[c], s3);
  }
  float4 k4; k4.x=s0; k4.y=s1; k4.z=s2; k4.w=s3;
  ((float4*)kbuf)[col] = k4;
#pragma unroll
  for (int o = 0; o < 16; ++o) {
    float s = vb[o];
#pragma unroll
    for (int c = 0; c < 16; ++c) s = fmaf(vw[o * 16 + c], hcv[c], s);
    vbuf[((size_t)b * 16 + o) * 2048 + n] = s;
  }
}

// ---------------------------------------------------------------- pass A: row softmax denominators (split-m partials)
__global__ __launch_bounds__(256) void k_rowstats(const float* __restrict__ kbuf, float* __restrict__ Lpart)
{
  __shared__ float4 kch[512];
  int bid = blockIdx.x;
  int b = bid >> 5, nt = (bid >> 2) & 7, ms = bid & 3;
  int tid = threadIdx.x;
  const float4* kb = (const float4*)kbuf + b * 2048;
  for (int i = tid; i < 512; i += 256) kch[i] = kb[ms * 512 + i];
  __syncthreads();
  int n = nt * 256 + tid;
  float4 q = kb[n];
  float L = 0.f;
#pragma unroll 4
  for (int m = 0; m < 512; ++m) {
    float4 kk = kch[m];
    float s = fmaf(q.x, kk.x, fmaf(q.y, kk.y, fmaf(q.z, kk.z, q.w * kk.w)));
    L += __expf(s);
  }
  Lpart[(ms * 16 + b) * 2048 + n] = L;
}

// ---------------------------------------------------------------- pass B: column accumulation (split-n partials)
__global__ __launch_bounds__(256) void k_colaccum(const float* __restrict__ kbuf, const float* __restrict__ vbuf,
    const float* __restrict__ Lpart, float* __restrict__ parts)
{
  __shared__ float ku[256 * 8];
  __shared__ float vch[256 * 16];
  int bid = blockIdx.x;
  int b = bid >> 5, mtl = (bid >> 2) & 7, ns = bid & 3;
  int tid = threadIdx.x;
  int m = mtl * 256 + tid;
  float4 q = ((const float4*)kbuf)[b * 2048 + m];
  float den = 0.f, acc[16];
#pragma unroll
  for (int c = 0; c < 16; ++c) acc[c] = 0.f;
  for (int ch = 0; ch < 2; ++ch) {
    int n0 = ns * 512 + ch * 256;
    __syncthreads();
    {
      int n = n0 + tid;
      float4 kk = ((const float4*)kbuf)[b * 2048 + n];
      float Ls = Lpart[(0 * 16 + b) * 2048 + n] + Lpart[(1 * 16 + b) * 2048 + n]
               + Lpart[(2 * 16 + b) * 2048 + n] + Lpart[(3 * 16 + b) * 2048 + n];
      *(float4*)&ku[tid * 8] = kk;
      ku[tid * 8 + 4] = 1.0f / Ls;
#pragma unroll
      for (int c = 0; c < 16; ++c) vch[tid * 16 + c] = vbuf[((size_t)b * 16 + c) * 2048 + n];
    }
    __syncthreads();
#pragma unroll 2
    for (int nn = 0; nn < 256; ++nn) {
      float4 kk = *(const float4*)&ku[nn * 8];
      float u = ku[nn * 8 + 4];
      float s = fmaf(q.x, kk.x, fmaf(q.y, kk.y, fmaf(q.z, kk.z, q.w * kk.w)));
      float e = __expf(s) * u;
      den += e;
      const float4* vp = (const float4*)&vch[nn * 16];
      float4 v0 = vp[0], v1 = vp[1], v2 = vp[2], v3 = vp[3];
      acc[0]=fmaf(e,v0.x,acc[0]);   acc[1]=fmaf(e,v0.y,acc[1]);
      acc[2]=fmaf(e,v0.z,acc[2]);   acc[3]=fmaf(e,v0.w,acc[3]);
      acc[4]=fmaf(e,v1.x,acc[4]);   acc[5]=fmaf(e,v1.y,acc[5]);
      acc[6]=fmaf(e,v1.z,acc[6]);   acc[7]=fmaf(e,v1.w,acc[7]);
      acc[8]=fmaf(e,v2.x,acc[8]);   acc[9]=fmaf(e,v2.y,acc[9]);
      acc[10]=fmaf(e,v2.z,acc[10]); acc[11]=fmaf(e,v2.w,acc[11]);
      acc[12]=fmaf(e,v3.x,acc[12]); acc[13]=fmaf(e,v3.y,acc[13]);
      acc[14]=fmaf(e,v3.z,acc[14]); acc[15]=fmaf(e,v3.w,acc[15]);
    }
  }
  float* p = parts + ((size_t)(ns * 16 + b) * 17) * 2048 + m;
#pragma unroll
  for (int c = 0; c < 16; ++c) p[(size_t)c * 2048] = acc[c];
  p[(size_t)16 * 2048] = den;
}

// ---------------------------------------------------------------- SA epilogue: combine + trans/bn/relu + residual (+ next k/v)
__global__ __launch_bounds__(128) void k_epilogue(const float* __restrict__ parts,
    const float* __restrict__ hin, int hbs, const float* __restrict__ t_w,
    const float* __restrict__ params, int layer, float* __restrict__ hout,
    const float* __restrict__ qk_w, const float* __restrict__ v_w, const float* __restrict__ v_b,
    float* __restrict__ kbuf, float* __restrict__ vbuf)
{
  __shared__ float tw[256], qk[64], vw[256], vb[16], sc[16], sh[16];
  int tid = threadIdx.x;
  for (int i = tid; i < 256; i += 128) tw[i] = t_w[i];
  if (qk_w) {
    if (tid < 64) qk[tid] = qk_w[tid];
    for (int i = tid; i < 256; i += 128) vw[i] = v_w[i];
    if (tid < 16) vb[tid] = v_b[tid];
  }
  if (tid < 16) { sc[tid] = params[288 + layer * 16 + tid]; sh[tid] = params[352 + layer * 16 + tid]; }
  __syncthreads();
  int col = blockIdx.x * 128 + tid;
  int b = col >> 11, n = col & 2047;
  float num[16], den = 0.f;
#pragma unroll
  for (int c = 0; c < 16; ++c) num[c] = 0.f;
#pragma unroll
  for (int s = 0; s < 4; ++s) {
    const float* p = parts + ((size_t)(s * 16 + b) * 17) * 2048 + n;
#pragma unroll
    for (int c = 0; c < 16; ++c) num[c] += p[(size_t)c * 2048];
    den += p[(size_t)16 * 2048];
  }
  float inv = 1.f / (1e-9f + den);
  const float* hc = hin + (size_t)b * hbs + n;
  float h[16], d[16];
#pragma unroll
  for (int c = 0; c < 16; ++c) { h[c] = hc[(size_t)c * 2048]; d[c] = h[c] - num[c] * inv; }
  float* out = hout + (size_t)b * 64 * 2048 + n;
  float hv[16];
#pragma unroll
  for (int o = 0; o < 16; ++o) {
    float y = 0.f;
#pragma unroll
    for (int c = 0; c < 16; ++c) y = fmaf(tw[o * 16 + c], d[c], y);
    y = relu_(fmaf(y, sc[o], sh[o]));
    hv[o] = h[o] + y;
    out[(size_t)o * 2048] = hv[o];
  }
  if (qk_w) {
    float s0=0.f,s1=0.f,s2=0.f,s3=0.f;
#pragma unroll
    for (int c = 0; c < 16; ++c) {
      s0 = fmaf(qk[c], hv[c], s0);  s1 = fmaf(qk[16+c], hv[c], s1);
      s2 = fmaf(qk[32+c], hv[c], s2); s3 = fmaf(qk[48+c], hv[c], s3);
    }
    float4 k4; k4.x=s0; k4.y=s1; k4.z=s2; k4.w=s3;
    ((float4*)kbuf)[col] = k4;
#pragma unroll
    for (int o = 0; o < 16; ++o) {
      float s = vb[o];
#pragma unroll
      for (int c = 0; c < 16; ++c) s = fmaf(vw[o * 16 + c], hv[c], s);
      vbuf[((size_t)b * 16 + o) * 2048 + n] = s;
    }
  }
}

// ---------------------------------------------------------------- fuse conv (64->128) + bn + leaky relu
__global__ __launch_bounds__(128) void k_fuse(const float* __restrict__ feats, const float* __restrict__ fw,
    const float* __restrict__ params, float* __restrict__ xqqw, bf16_t* __restrict__ gbuf)
{
  __shared__ float ws[8192];
  __shared__ float sc[128], sh[128];
  int tid = threadIdx.x;
  for (int i = tid; i < 8192; i += 128) ws[i] = fw[i];
  if (tid < 128) { sc[tid] = params[416 + tid]; sh[tid] = params[544 + tid]; }
  __syncthreads();
  int col = blockIdx.x * 128 + tid;
  int b = col >> 11, n = col & 2047;
  const float* f = feats + (size_t)b * 64 * 2048 + n;
  float fv[64];
#pragma unroll
  for (int c = 0; c < 64; ++c) fv[c] = f[(size_t)c * 2048];
  float* xq = xqqw + (size_t)b * 128 * 2048 + n;
  bf16_t* g = gbuf + (size_t)col * 288;
  for (int o0 = 0; o0 < 128; o0 += 8) {
    bf16x8 pk;
#pragma unroll
    for (int oo = 0; oo < 8; ++oo) {
      int o = o0 + oo;
      float s = 0.f;
#pragma unroll
      for (int c = 0; c < 64; ++c) s = fmaf(ws[o * 64 + c], fv[c], s);
      s = fmaf(s, sc[o], sh[o]);
      s = s > 0.f ? s : 0.2f * s;
      xq[(size_t)o * 2048] = s;
      pk[oo] = (bf16_t)s;
    }
    *(bf16x8*)(g + o0) = pk;
  }
}

// ---------------------------------------------------------------- argmax over n (+ batch-1 channel means)
__global__ __launch_bounds__(256) void k_argmax(const float* __restrict__ xqqw,
    float* __restrict__ xmaxf, float* __restrict__ xavg)
{
  __shared__ float sv[256]; __shared__ int si[256]; __shared__ float ss[256];
  int bo = blockIdx.x;                     // b*128+o
  int b = bo >> 7, o = bo & 127;
  const float* row = xqqw + (size_t)bo * 2048;
  int tid = threadIdx.x;
  float best = -3.4e38f; int bi = 0; float sum = 0.f;
#pragma unroll
  for (int j = 0; j < 8; ++j) {
    int n = j * 256 + tid;
    float v = row[n];
    sum += v;
    if (v > best) { best = v; bi = n; }
  }
  sv[tid] = best; si[tid] = bi; ss[tid] = sum;
  __syncthreads();
  for (int s = 128; s > 0; s >>= 1) {
    if (tid < s) {
      float v2 = sv[tid + s]; int i2 = si[tid + s];
      if (v2 > sv[tid] || (v2 == sv[tid] && i2 < si[tid])) { sv[tid] = v2; si[tid] = i2; }
      ss[tid] += ss[tid + s];
    }
    __syncthreads();
  }
  if (tid == 0) {
    xmaxf[bo] = (float)si[0];
    if (b == 1) xavg[o] = ss[0] * (1.0f / 2048.0f);
  }
}

// ---------------------------------------------------------------- fill g rows 128..287 (xmax, xavg, zero pad)
__global__ __launch_bounds__(256) void k_fillg(const float* __restrict__ xmaxf, const float* __restrict__ xavg,
    bf16_t* __restrict__ gbuf)
{
  __shared__ bf16_t mx[128]; __shared__ bf16_t av[8];
  int tid = threadIdx.x;
  int col = blockIdx.x * 256 + tid;
  int b = col >> 11;
  if (tid < 128) mx[tid] = (bf16_t)xmaxf[b * 128 + tid];
  if (tid < 8) av[tid] = (bf16_t)xavg[b * 8 + tid];
  __syncthreads();
  bf16_t* g = gbuf + (size_t)col * 288;
#pragma unroll
  for (int o0 = 0; o0 < 128; o0 += 8)
    *(bf16x8*)(g + 128 + o0) = *(const bf16x8*)&mx[o0];
  *(bf16x8*)(g + 256) = *(const bf16x8*)&av[0];
  bf16x8 zv;
#pragma unroll
  for (int i = 0; i < 8; ++i) zv[i] = (bf16_t)0.f;
  *(bf16x8*)(g + 264) = zv;
  *(bf16x8*)(g + 272) = zv;
  *(bf16x8*)(g + 280) = zv;
}

// ---------------------------------------------------------------- bf16 MFMA GEMM: C[bn][o] = relu(bn(A[o][:] . B[bn][:]))
// A [M][K], Bm [32768][K] (both K-contiguous), Cout [32768][M] bf16. 128x128 tiles, BK=32.
__global__ __launch_bounds__(256) void k_gemm(const bf16_t* __restrict__ A, const bf16_t* __restrict__ Bm,
    const float* __restrict__ scp, const float* __restrict__ shp, bf16_t* __restrict__ Cout,
    int M, int K, int mtiles)
{
  __shared__ bf16_t At[128 * 32];
  __shared__ bf16_t Bt[128 * 32];
  int tid = threadIdx.x;
  int mt = blockIdx.x % mtiles, ct = blockIdx.x / mtiles;
  int srow = tid >> 2, scol = (tid & 3) << 3;     // 64 rows per 256 threads, x2 below
  const bf16_t* ga = A  + (size_t)(mt * 128 + srow) * K + scol;
  const bf16_t* gb = Bm + (size_t)(ct * 128 + srow) * K + scol;
  int lane = tid & 63, wave = tid >> 6;
  int wr = (wave >> 1) * 64, wc = (wave & 1) * 64;
  int frow = lane & 15, fk = (lane >> 4) * 8;
  const f32x4 z4 = {0.f, 0.f, 0.f, 0.f};
  f32x4 acc[4][4];
#pragma unroll
  for (int i = 0; i < 4; ++i)
#pragma unroll
    for (int j = 0; j < 4; ++j) acc[i][j] = z4;
  uint4 ra0 = *(const uint4*)ga, ra1 = *(const uint4*)(ga + (size_t)64 * K);
  uint4 rb0 = *(const uint4*)gb, rb1 = *(const uint4*)(gb + (size_t)64 * K);
  int ksteps = K >> 5;
  for (int ks = 0; ks < ksteps; ++ks) {
    __syncthreads();
    *(uint4*)&At[tid * 8] = ra0;  *(uint4*)&At[2048 + tid * 8] = ra1;
    *(uint4*)&Bt[tid * 8] = rb0;  *(uint4*)&Bt[2048 + tid * 8] = rb1;
    __syncthreads();
    if (ks + 1 < ksteps) {
      ra0 = *(const uint4*)(ga + (ks + 1) * 32);
      ra1 = *(const uint4*)(ga + (size_t)64 * K + (ks + 1) * 32);
      rb0 = *(const uint4*)(gb + (ks + 1) * 32);
      rb1 = *(const uint4*)(gb + (size_t)64 * K + (ks + 1) * 32);
    }
    bf16x8 af[4], bfr[4];
#pragma unroll
    for (int i = 0; i < 4; ++i) af[i]  = *(const bf16x8*)&At[(wr + i * 16 + frow) * 32 + fk];
#pragma unroll
    for (int j = 0; j < 4; ++j) bfr[j] = *(const bf16x8*)&Bt[(wc + j * 16 + frow) * 32 + fk];
#pragma unroll
    for (int i = 0; i < 4; ++i)
#pragma unroll
      for (int j = 0; j < 4; ++j)
        acc[i][j] = __builtin_amdgcn_mfma_f32_16x16x32_bf16(af[i], bfr[j], acc[i][j], 0, 0, 0);
  }
  int crow = (lane >> 4) * 4, ccol = lane & 15;
#pragma unroll
  for (int i = 0; i < 4; ++i) {
    int o0 = mt * 128 + wr + i * 16 + crow;
    float s0 = scp[o0], s1 = scp[o0+1], s2 = scp[o0+2], s3 = scp[o0+3];
    float t0 = shp[o0], t1 = shp[o0+1], t2 = shp[o0+2], t3 = shp[o0+3];
#pragma unroll
    for (int j = 0; j < 4; ++j) {
      int bn = ct * 128 + wc + j * 16 + ccol;
      bf16x4 pk;
      pk[0] = (bf16_t)relu_(fmaf(acc[i][j][0], s0, t0));
      pk[1] = (bf16_t)relu_(fmaf(acc[i][j][1], s1, t1));
      pk[2] = (bf16_t)relu_(fmaf(acc[i][j][2], s2, t2));
      pk[3] = (bf16_t)relu_(fmaf(acc[i][j][3], s3, t3));
      *(bf16x4*)(Cout + (size_t)bn * M + o0) = pk;
    }
  }
}

// ---------------------------------------------------------------- convs3 (256->16) + bias, fp32 out
__global__ __launch_bounds__(128) void k_gemm3(const bf16_t* __restrict__ g2, const float* __restrict__ w3,
    const float* __restrict__ b3, float* __restrict__ out)
{
  __shared__ float wsT[4096];   // [k][o]
  __shared__ float bb[16];
  int tid = threadIdx.x;
  for (int i = tid; i < 4096; i += 128) { int o = i >> 8, k = i & 255; wsT[k * 16 + o] = w3[i]; }
  if (tid < 16) bb[tid] = b3[tid];
  __syncthreads();
  int col = blockIdx.x * 128 + tid;
  int b = col >> 11, n = col & 2047;
  const bf16_t* g = g2 + (size_t)col * 256;
  float acc[16];
#pragma unroll
  for (int o = 0; o < 16; ++o) acc[o] = 0.f;
  for (int k0 = 0; k0 < 256; k0 += 8) {
    bf16x8 gv8 = *(const bf16x8*)(g + k0);
#pragma unroll
    for (int kk = 0; kk < 8; ++kk) {
      float gv = (float)gv8[kk];
      const float* wr = &wsT[(k0 + kk) * 16];
#pragma unroll
      for (int o = 0; o < 16; ++o) acc[o] = fmaf(wr[o], gv, acc[o]);
    }
  }
  float* op = out + (size_t)b * 16 * 2048 + n;
#pragma unroll
  for (int o = 0; o < 16; ++o) op[(size_t)o * 2048] = acc[o] + bb[o];
}

// ---------------------------------------------------------------- launch
extern "C" void kernel_launch(void* const* d_in, const int* in_sizes, int n_in,
                              void* d_out, int out_size, void* d_ws, size_t ws_size,
                              hipStream_t stream)
{
  const float* x         = (const float*)d_in[0];
  const float* conv1_w   = (const float*)d_in[1];
  const float* bn1       = (const float*)d_in[2];
  const float* conv2_w   = (const float*)d_in[3];
  const float* bn2       = (const float*)d_in[4];
  const float* sa_qk_w   = (const float*)d_in[5];
  const float* sa_v_w    = (const float*)d_in[6];
  const float* sa_v_b    = (const float*)d_in[7];
  const float* sa_trans_w= (const float*)d_in[8];
  const float* sa_trans_b= (const float*)d_in[9];
  const float* sa_bn     = (const float*)d_in[10];
  const float* fuse_w    = (const float*)d_in[11];
  const float* fuse_bn   = (const float*)d_in[12];
  const float* convs1_w  = (const float*)d_in[13];
  const float* convs1_b  = (const float*)d_in[14];
  const float* bns1      = (const float*)d_in[15];
  const float* convs2_w  = (const float*)d_in[16];
  const float* convs2_b  = (const float*)d_in[17];
  const float* bns2      = (const float*)d_in[18];
  const float* convs3_w  = (const float*)d_in[19];
  const float* convs3_b  = (const float*)d_in[20];

  char* ws = (char*)d_ws;
  float*  h1    = (float*)(ws + 0);
  float*  h0    = (float*)(ws + 16777216);
  float*  feats = (float*)(ws + 18874368);
  float*  xqqw  = (float*)(ws + 27262976);
  float*  kbuf  = (float*)(ws + 44040192);
  float*  vbuf  = (float*)(ws + 44564480);
  float*  Lpart = (float*)(ws + 46661632);
  float*  parts = (float*)(ws + 47185920);
  bf16_t* g1    = (bf16_t*)(ws + 0);          // overlays h1/h0/feats (dead by then)
  bf16_t* g2    = (bf16_t*)(ws + 33554432);   // overlays xqqw tail + attn scratch (dead)
  bf16_t* gbuf  = (bf16_t*)(ws + 56098816);
  bf16_t* wbuf1 = (bf16_t*)(ws + 74973184);
  bf16_t* wbuf2 = (bf16_t*)(ws + 75268096);
  float*  params= (float*)(ws + 75530240);
  float*  xmaxf = (float*)(ws + 75546624);
  float*  xavg  = (float*)(ws + 75554816);

  k_prep<<<256, 256, 0, stream>>>(convs1_w, convs2_w, bn1, bn2, sa_bn, sa_trans_b, fuse_bn,
                                  convs1_b, bns1, convs2_b, bns2, wbuf1, wbuf2, params);
  k_conv1<<<256, 128, 0, stream>>>(x, conv1_w, params, h1);
  k_conv2kv<<<256, 128, 0, stream>>>(h1, conv2_w, params, sa_qk_w, sa_v_w, sa_v_b, h0, kbuf, vbuf);
  for (int i = 0; i < 4; ++i) {
    k_rowstats<<<512, 256, 0, stream>>>(kbuf, Lpart);
    k_colaccum<<<512, 256, 0, stream>>>(kbuf, vbuf, Lpart, parts);
    const float* hin = (i == 0) ? h0 : (feats + (size_t)(i - 1) * 16 * 2048);
    int hbs = (i == 0) ? 16 * 2048 : 64 * 2048;
    bool last = (i == 3);
    k_epilogue<<<256, 128, 0, stream>>>(parts, hin, hbs, sa_trans_w + i * 256, params, i,
        feats + (size_t)i * 16 * 2048,
        last ? nullptr : sa_qk_w + (i + 1) * 64,
        last ? nullptr : sa_v_w + (i + 1) * 256,
        last ? nullptr : sa_v_b + (i + 1) * 16,
        kbuf, vbuf);
  }
  k_fuse<<<256, 128, 0, stream>>>(feats, fuse_w, params, xqqw, gbuf);
  k_argmax<<<2048, 256, 0, stream>>>(xqqw, xmaxf, xavg);
  k_fillg<<<128, 256, 0, stream>>>(xmaxf, xavg, gbuf);
  k_gemm<<<1024, 256, 0, stream>>>(wbuf1, gbuf, params + 672, params + 1184, g1, 512, 288, 4);
  k_gemm<<<512, 256, 0, stream>>>(wbuf2, g1, params + 1696, params + 1952, g2, 256, 512, 2);
  k_gemm3<<<256, 128, 0, stream>>>(g2, convs3_w, convs3_b, (float*)d_out);
}

// Round 2
// 564.411 us; speedup vs baseline: 1.0283x; 1.0283x over previous
//
#include <hip/hip_runtime.h>
#include <stdint.h>

typedef __bf16 bf16_t;
typedef __bf16 bf16x8 __attribute__((ext_vector_type(8)));
typedef __bf16 bf16x4 __attribute__((ext_vector_type(4)));
typedef float f32x4 __attribute__((ext_vector_type(4)));
typedef float f32x2 __attribute__((ext_vector_type(2)));

#define LOG2E 1.4426950408889634f

__device__ __forceinline__ float relu_(float v) { return v > 0.f ? v : 0.f; }

// ---------------------------------------------------------------- prep
// params layout (floats):
// 0 bn1_scale[128] |128 bn1_shift[128] |256 bn2_scale[16] |272 bn2_shift[16]
// 288 sa_scale[64] |352 sa_shift[64] |416 fuse_scale[128] |544 fuse_shift[128]
// 672 bns1_scale[512] |1184 bns1_shift[512] |1696 bns2_scale[256] |1952 bns2_shift[256]
__global__ __launch_bounds__(256) void k_prep(
    const float* __restrict__ convs1_w, const float* __restrict__ convs2_w,
    const float* __restrict__ bn1, const float* __restrict__ bn2,
    const float* __restrict__ sa_bn, const float* __restrict__ sa_trans_b,
    const float* __restrict__ fuse_bn, const float* __restrict__ convs1_b,
    const float* __restrict__ bns1, const float* __restrict__ convs2_b,
    const float* __restrict__ bns2,
    bf16_t* __restrict__ wbuf1, bf16_t* __restrict__ wbuf2, float* __restrict__ params)
{
  int idx = blockIdx.x * 256 + threadIdx.x;
  for (int it = 0; it < 3; ++it) {
    int i = idx + it * 65536;
    if (i < 65536) {                        // wbuf1 [512][128] = first 128 cols of convs1_w
      int o = i >> 7, c = i & 127;
      wbuf1[i] = (bf16_t)convs1_w[o * 264 + c];
    } else if (i < 65536 + 131072) {        // wbuf2 [256][512]
      int j = i - 65536;
      wbuf2[j] = (bf16_t)convs2_w[j];
    }
  }
  if (blockIdx.x == 0) {
    for (int t = threadIdx.x; t < 1104; t += 256) {
      float g, be, m, v, extra = 0.f; int so, ho;
      if (t < 128)      { g=bn1[t]; be=bn1[128+t]; m=bn1[256+t]; v=bn1[384+t]; so=t; ho=128+t; }
      else if (t < 144) { int u=t-128; g=bn2[u]; be=bn2[16+u]; m=bn2[32+u]; v=bn2[48+u]; so=256+u; ho=272+u; }
      else if (t < 208) { int u=t-144; int L=u>>4, o=u&15; const float* p=sa_bn+L*64;
                          g=p[o]; be=p[16+o]; m=p[32+o]; v=p[48+o];
                          extra=sa_trans_b[L*16+o]; so=288+u; ho=352+u; }
      else if (t < 336) { int u=t-208; g=fuse_bn[u]; be=fuse_bn[128+u]; m=fuse_bn[256+u]; v=fuse_bn[384+u]; so=416+u; ho=544+u; }
      else if (t < 848) { int u=t-336; g=bns1[u]; be=bns1[512+u]; m=bns1[1024+u]; v=bns1[1536+u]; extra=convs1_b[u]; so=672+u; ho=1184+u; }
      else              { int u=t-848; g=bns2[u]; be=bns2[256+u]; m=bns2[512+u]; v=bns2[768+u]; extra=convs2_b[u]; so=1696+u; ho=1952+u; }
      float sc = g * rsqrtf(v + 1e-5f);
      params[so] = sc;
      params[ho] = (extra - m) * sc + be;
    }
  }
}

// ---------------------------------------------------------------- fused conv1(16->128)+bn+relu -> conv2(128->16)+bn+relu -> layer0 k/v
__global__ __launch_bounds__(256) void k_convs(const float* __restrict__ x,
    const float* __restrict__ w1, const float* __restrict__ w2,
    const float* __restrict__ params, const float* __restrict__ qk_w,
    const float* __restrict__ v_w, const float* __restrict__ v_b,
    float* __restrict__ h0, float* __restrict__ kbuf, float* __restrict__ vbuf)
{
  __shared__ __align__(16) float xs[16 * 128];
  __shared__ float ws1[128 * 17];
  __shared__ float ws2[16 * 129];
  __shared__ __align__(16) float h1s[128 * 64];
  __shared__ float hcv[128 * 17];
  __shared__ float qk[64], vw[256], vb[16], sc1[128], sh1[128], sc2[16], sh2[16];
  int t = threadIdx.x;
  int bid = blockIdx.x;                       // 256 = b*16 + chunk(128 cols)
  int b = bid >> 4, n0 = (bid & 15) * 128;
  for (int i = t; i < 2048; i += 256) { int c = i >> 7, col = i & 127; xs[c * 128 + col] = x[((size_t)b * 16 + c) * 2048 + n0 + col]; }
  for (int i = t; i < 2048; i += 256) { int o = i >> 4, c = i & 15;  ws1[o * 17 + c]  = w1[i]; }
  for (int i = t; i < 2048; i += 256) { int o = i >> 7, c = i & 127; ws2[o * 129 + c] = w2[i]; }
  if (t < 64) qk[t] = qk_w[t];
  vw[t] = v_w[t];
  if (t < 16) { vb[t] = v_b[t]; sc2[t] = params[256 + t]; sh2[t] = params[272 + t]; }
  if (t < 128) { sc1[t] = params[t]; sh1[t] = params[128 + t]; }
  __syncthreads();
  int colh = t & 63, hi4 = t >> 6;
  int cg = t & 15, og = t >> 4;
  for (int h = 0; h < 2; ++h) {
    int cb = h * 64;
    // phase B: conv1 for 64 cols, all 128 outs
    float xr[16];
#pragma unroll
    for (int c = 0; c < 16; ++c) xr[c] = xs[c * 128 + cb + colh];
#pragma unroll 4
    for (int i = 0; i < 32; ++i) {
      int o = (i << 2) | hi4;
      float s = 0.f;
#pragma unroll
      for (int c = 0; c < 16; ++c) s = fmaf(ws1[o * 17 + c], xr[c], s);
      h1s[o * 64 + colh] = relu_(fmaf(s, sc1[o], sh1[o]));
    }
    __syncthreads();
    // phase C: conv2 (128->16) for the 64 cols
    float a0 = 0.f, a1 = 0.f, a2 = 0.f, a3 = 0.f;
    for (int c = 0; c < 128; ++c) {
      float4 f = *(const float4*)&h1s[c * 64 + cg * 4];
      float w = ws2[og * 129 + c];
      a0 = fmaf(w, f.x, a0); a1 = fmaf(w, f.y, a1);
      a2 = fmaf(w, f.z, a2); a3 = fmaf(w, f.w, a3);
    }
    float4 v4;
    v4.x = relu_(fmaf(a0, sc2[og], sh2[og]));
    v4.y = relu_(fmaf(a1, sc2[og], sh2[og]));
    v4.z = relu_(fmaf(a2, sc2[og], sh2[og]));
    v4.w = relu_(fmaf(a3, sc2[og], sh2[og]));
    *(float4*)&h0[((size_t)b * 16 + og) * 2048 + n0 + cb + cg * 4] = v4;
    hcv[(cb + cg * 4 + 0) * 17 + og] = v4.x;
    hcv[(cb + cg * 4 + 1) * 17 + og] = v4.y;
    hcv[(cb + cg * 4 + 2) * 17 + og] = v4.z;
    hcv[(cb + cg * 4 + 3) * 17 + og] = v4.w;
    __syncthreads();
  }
  // phase D: k (4 outs) + v (16 outs) projections
  int col = t & 127, ug = t >> 7;
  float hr[16];
#pragma unroll
  for (int c = 0; c < 16; ++c) hr[c] = hcv[col * 17 + c];
#pragma unroll
  for (int i = 0; i < 10; ++i) {
    int u = ug * 10 + i;
    const float* W = (u < 4) ? &qk[u * 16] : &vw[(u - 4) * 16];
    float s = (u < 4) ? 0.f : vb[u - 4];
#pragma unroll
    for (int c = 0; c < 16; ++c) s = fmaf(W[c], hr[c], s);
    if (u < 4) kbuf[((size_t)b * 2048 + n0 + col) * 4 + u] = s;
    else       vbuf[((size_t)b * 16 + (u - 4)) * 2048 + n0 + col] = s;
  }
}

// ---------------------------------------------------------------- pass A: row softmax denominators (8 m-splits)
__global__ __launch_bounds__(256) void k_rowstats(const float* __restrict__ kbuf, float* __restrict__ Lpart)
{
  __shared__ float4 kch[256];
  int bid = blockIdx.x;                     // 1024 = b*64 + nt*8 + ms
  int b = bid >> 6, nt = (bid >> 3) & 7, ms = bid & 7;
  int t = threadIdx.x;
  const float4* kb = (const float4*)kbuf + b * 2048;
  kch[t] = kb[ms * 256 + t];
  __syncthreads();
  int n = nt * 256 + t;
  float4 q = kb[n];
  q.x *= LOG2E; q.y *= LOG2E; q.z *= LOG2E; q.w *= LOG2E;
  float L = 0.f;
#pragma unroll 4
  for (int m = 0; m < 256; ++m) {
    float4 k4 = kch[m];
    float s = fmaf(q.x, k4.x, fmaf(q.y, k4.y, fmaf(q.z, k4.z, q.w * k4.w)));
    L += exp2f(s);
  }
  Lpart[((size_t)ms * 16 + b) * 2048 + n] = L;
}

// ---------------------------------------------------------------- pass B: column accumulation (4 n-splits, packed f32x2)
__global__ __launch_bounds__(256) void k_colaccum(const float* __restrict__ kbuf, const float* __restrict__ vbuf,
    const float* __restrict__ Lpart, float* __restrict__ parts)
{
  __shared__ __align__(16) float ku[512 * 8];
  __shared__ __align__(16) float vch[512 * 16];
  int bid = blockIdx.x;                     // 512 = b*32 + mt*4 + ns
  int b = bid >> 5, mt = (bid >> 2) & 7, ns = bid & 3;
  int t = threadIdx.x;
  int m = mt * 256 + t;
  float4 q = ((const float4*)kbuf)[b * 2048 + m];
  f32x2 q01 = {q.x * LOG2E, q.y * LOG2E};
  f32x2 q23 = {q.z * LOG2E, q.w * LOG2E};
  for (int i = t; i < 512; i += 256) {
    int n = ns * 512 + i;
    float4 kk = ((const float4*)kbuf)[b * 2048 + n];
    float Ls = 0.f;
#pragma unroll
    for (int s = 0; s < 8; ++s) Ls += Lpart[((size_t)s * 16 + b) * 2048 + n];
    *(float4*)&ku[i * 8] = kk;
    ku[i * 8 + 4] = 1.0f / Ls;
#pragma unroll
    for (int c = 0; c < 16; ++c) vch[i * 16 + c] = vbuf[((size_t)b * 16 + c) * 2048 + n];
  }
  __syncthreads();
  f32x2 acc[8];
#pragma unroll
  for (int j = 0; j < 8; ++j) acc[j] = (f32x2){0.f, 0.f};
  float den = 0.f;
#pragma unroll 2
  for (int nn = 0; nn < 512; ++nn) {
    const f32x2* kp = (const f32x2*)&ku[nn * 8];
    f32x2 p = q01 * kp[0];
    p = q23 * kp[1] + p;
    float s = p[0] + p[1];
    float e = exp2f(s) * ku[nn * 8 + 4];
    den += e;
    f32x2 ev = {e, e};
    const f32x2* vp = (const f32x2*)&vch[nn * 16];
    acc[0] += ev * vp[0]; acc[1] += ev * vp[1];
    acc[2] += ev * vp[2]; acc[3] += ev * vp[3];
    acc[4] += ev * vp[4]; acc[5] += ev * vp[5];
    acc[6] += ev * vp[6]; acc[7] += ev * vp[7];
  }
  float* p = parts + ((size_t)(ns * 16 + b) * 17) * 2048 + m;
#pragma unroll
  for (int c = 0; c < 16; ++c) p[(size_t)c * 2048] = acc[c >> 1][c & 1];
  p[(size_t)16 * 2048] = den;
}

// ---------------------------------------------------------------- SA epilogue: combine + trans/bn/relu + residual (+ next k/v)
__global__ __launch_bounds__(256) void k_epilogue(const float* __restrict__ parts,
    const float* __restrict__ hin, int hbs, const float* __restrict__ t_w,
    const float* __restrict__ params, int layer, float* __restrict__ hout,
    const float* __restrict__ qk_w, const float* __restrict__ v_w, const float* __restrict__ v_b,
    float* __restrict__ kbuf, float* __restrict__ vbuf)
{
  __shared__ float pd[17 * 64];
  __shared__ float hs[16 * 64];
  __shared__ float dl[16 * 64];
  __shared__ float hv[64 * 17];
  __shared__ float tw[256], qk[64], vw[256], vb[16], sc[16], sh[16];
  int t = threadIdx.x;
  int bid = blockIdx.x;                     // 512 = b*32 + chunk(64 cols)
  int b = bid >> 5, n0 = (bid & 31) * 64;
  tw[t] = t_w[t];
  if (qk_w) { if (t < 64) qk[t] = qk_w[t]; vw[t] = v_w[t]; if (t < 16) vb[t] = v_b[t]; }
  if (t < 16) { sc[t] = params[288 + layer * 16 + t]; sh[t] = params[352 + layer * 16 + t]; }
  for (int i = t; i < 1088; i += 256) {
    int r = i >> 6, c = i & 63;
    float s = 0.f;
#pragma unroll
    for (int sp = 0; sp < 4; ++sp)
      s += parts[((size_t)(sp * 16 + b) * 17 + r) * 2048 + n0 + c];
    pd[i] = s;
  }
  for (int i = t; i < 1024; i += 256) {
    int c = i >> 6, col = i & 63;
    hs[i] = hin[(size_t)b * hbs + (size_t)c * 2048 + n0 + col];
  }
  __syncthreads();
  int col = t & 63, g4 = t >> 6;
  float inv = 1.f / (1e-9f + pd[16 * 64 + col]);
#pragma unroll
  for (int j = 0; j < 4; ++j) {
    int c = g4 * 4 + j;
    dl[c * 64 + col] = hs[c * 64 + col] - pd[c * 64 + col] * inv;
  }
  __syncthreads();
#pragma unroll
  for (int j = 0; j < 4; ++j) {
    int o = g4 * 4 + j;
    float y = 0.f;
#pragma unroll
    for (int c = 0; c < 16; ++c) y = fmaf(tw[o * 16 + c], dl[c * 64 + col], y);
    y = relu_(fmaf(y, sc[o], sh[o]));
    float hh = hs[o * 64 + col] + y;
    hout[(size_t)b * 64 * 2048 + (size_t)o * 2048 + n0 + col] = hh;
    hv[col * 17 + o] = hh;
  }
  if (qk_w) {
    __syncthreads();
    float hr[16];
#pragma unroll
    for (int c = 0; c < 16; ++c) hr[c] = hv[col * 17 + c];
#pragma unroll
    for (int i = 0; i < 5; ++i) {
      int u = g4 * 5 + i;
      const float* W = (u < 4) ? &qk[u * 16] : &vw[(u - 4) * 16];
      float s = (u < 4) ? 0.f : vb[u - 4];
#pragma unroll
      for (int c = 0; c < 16; ++c) s = fmaf(W[c], hr[c], s);
      if (u < 4) kbuf[((size_t)b * 2048 + n0 + col) * 4 + u] = s;
      else       vbuf[((size_t)b * 16 + (u - 4)) * 2048 + n0 + col] = s;
    }
  }
}

// ---------------------------------------------------------------- fuse conv (64->128) + bn + leaky relu
__global__ __launch_bounds__(256) void k_fuse(const float* __restrict__ feats, const float* __restrict__ fw,
    const float* __restrict__ params, float* __restrict__ xqqw, bf16_t* __restrict__ gbuf)
{
  __shared__ float ws[128 * 65];
  __shared__ __align__(16) float fst[64 * 64];
  __shared__ float sc[128], sh[128];
  int t = threadIdx.x, bid = blockIdx.x;    // 512 = b*32 + chunk(64 cols)
  int b = bid >> 5, n0 = (bid & 31) * 64;
  for (int i = t; i < 8192; i += 256) { int o = i >> 6, c = i & 63; ws[o * 65 + c] = fw[i]; }
  for (int i = t; i < 4096; i += 256) { int c = i >> 6, col = i & 63; fst[i] = feats[((size_t)b * 64 + c) * 2048 + n0 + col]; }
  if (t < 128) { sc[t] = params[416 + t]; sh[t] = params[544 + t]; }
  __syncthreads();
  int cg = t & 7, og = t >> 3;              // 8 col-grps(8 cols) x 32 out-grps(4 outs)
  f32x2 acc[4][4];
#pragma unroll
  for (int oo = 0; oo < 4; ++oo)
#pragma unroll
    for (int j = 0; j < 4; ++j) acc[oo][j] = (f32x2){0.f, 0.f};
  for (int c = 0; c < 64; ++c) {
    const f32x2* fp = (const f32x2*)&fst[c * 64 + cg * 8];
    f32x2 f0 = fp[0], f1 = fp[1], f2v = fp[2], f3 = fp[3];
#pragma unroll
    for (int oo = 0; oo < 4; ++oo) {
      float w = ws[(og * 4 + oo) * 65 + c];
      f32x2 wv = {w, w};
      acc[oo][0] += wv * f0; acc[oo][1] += wv * f1;
      acc[oo][2] += wv * f2v; acc[oo][3] += wv * f3;
    }
  }
  float y[4][8];
#pragma unroll
  for (int oo = 0; oo < 4; ++oo) {
    int o = og * 4 + oo;
    float s0 = sc[o], s1 = sh[o];
#pragma unroll
    for (int j = 0; j < 8; ++j) {
      float v = fmaf(acc[oo][j >> 1][j & 1], s0, s1);
      y[oo][j] = v > 0.f ? v : 0.2f * v;
    }
    float4 v0 = {y[oo][0], y[oo][1], y[oo][2], y[oo][3]};
    float4 v1 = {y[oo][4], y[oo][5], y[oo][6], y[oo][7]};
    *(float4*)&xqqw[((size_t)b * 128 + o) * 2048 + n0 + cg * 8] = v0;
    *(float4*)&xqqw[((size_t)b * 128 + o) * 2048 + n0 + cg * 8 + 4] = v1;
  }
#pragma unroll
  for (int j = 0; j < 8; ++j) {
    int col = n0 + cg * 8 + j;
    bf16x4 pk;
    pk[0] = (bf16_t)y[0][j]; pk[1] = (bf16_t)y[1][j];
    pk[2] = (bf16_t)y[2][j]; pk[3] = (bf16_t)y[3][j];
    *(bf16x4*)&gbuf[((size_t)b * 2048 + col) * 128 + og * 4] = pk;
  }
}

// ---------------------------------------------------------------- argmax over n (+ batch-1 channel means)
__global__ __launch_bounds__(256) void k_argmax(const float* __restrict__ xqqw,
    float* __restrict__ xmaxf, float* __restrict__ xavg)
{
  __shared__ float sv[256]; __shared__ int si[256]; __shared__ float ss[256];
  int bo = blockIdx.x;                     // b*128+o
  int b = bo >> 7, o = bo & 127;
  const float* row = xqqw + (size_t)bo * 2048;
  int tid = threadIdx.x;
  float best = -3.4e38f; int bi = 0; float sum = 0.f;
#pragma unroll
  for (int j = 0; j < 8; ++j) {
    int n = j * 256 + tid;
    float v = row[n];
    sum += v;
    if (v > best) { best = v; bi = n; }
  }
  sv[tid] = best; si[tid] = bi; ss[tid] = sum;
  __syncthreads();
  for (int s = 128; s > 0; s >>= 1) {
    if (tid < s) {
      float v2 = sv[tid + s]; int i2 = si[tid + s];
      if (v2 > sv[tid] || (v2 == sv[tid] && i2 < si[tid])) { sv[tid] = v2; si[tid] = i2; }
      ss[tid] += ss[tid + s];
    }
    __syncthreads();
  }
  if (tid == 0) {
    xmaxf[bo] = (float)si[0];
    if (b == 1) xavg[o] = ss[0] * (1.0f / 2048.0f);
  }
}

// ---------------------------------------------------------------- exact fp32 bias from x_max/x_avg rows (replaces g rows 128..287)
__global__ __launch_bounds__(256) void k_bias2(const float* __restrict__ w1,
    const float* __restrict__ xmaxf, const float* __restrict__ xavg,
    const float* __restrict__ params, float* __restrict__ bias2)
{
  int id = blockIdx.x * 256 + threadIdx.x;   // 8192 = o*16 + b
  int o = id >> 4, b = id & 15;
  const float* wr = w1 + (size_t)o * 264;
  float s = 0.f;
  for (int u = 0; u < 128; ++u) s = fmaf(wr[128 + u], xmaxf[b * 128 + u], s);
#pragma unroll
  for (int u = 0; u < 8; ++u)  s = fmaf(wr[256 + u], xavg[b * 8 + u], s);
  bias2[b * 512 + o] = s * params[672 + o];
}

// ---------------------------------------------------------------- bf16 MFMA GEMM: Cout[bn][o] = relu(bn(A[o][:].B[bn][:]) + bias2)
__global__ __launch_bounds__(256) void k_gemm(const bf16_t* __restrict__ A, const bf16_t* __restrict__ Bm,
    const float* __restrict__ scp, const float* __restrict__ shp, const float* __restrict__ bias2,
    bf16_t* __restrict__ Cout, int M, int K, int mtiles)
{
  __shared__ bf16_t At[128 * 32];
  __shared__ bf16_t Bt[128 * 32];
  int tid = threadIdx.x;
  int mt = blockIdx.x % mtiles, ct = blockIdx.x / mtiles;
  int srow = tid >> 2, scol = (tid & 3) << 3;
  const bf16_t* ga = A  + (size_t)(mt * 128 + srow) * K + scol;
  const bf16_t* gb = Bm + (size_t)(ct * 128 + srow) * K + scol;
  int lane = tid & 63, wave = tid >> 6;
  int wr = (wave >> 1) * 64, wc = (wave & 1) * 64;
  int frow = lane & 15, fk = (lane >> 4) * 8;
  const f32x4 z4 = {0.f, 0.f, 0.f, 0.f};
  f32x4 acc[4][4];
#pragma unroll
  for (int i = 0; i < 4; ++i)
#pragma unroll
    for (int j = 0; j < 4; ++j) acc[i][j] = z4;
  uint4 ra0 = *(const uint4*)ga, ra1 = *(const uint4*)(ga + (size_t)64 * K);
  uint4 rb0 = *(const uint4*)gb, rb1 = *(const uint4*)(gb + (size_t)64 * K);
  int ksteps = K >> 5;
  for (int ks = 0; ks < ksteps; ++ks) {
    __syncthreads();
    *(uint4*)&At[tid * 8] = ra0;  *(uint4*)&At[2048 + tid * 8] = ra1;
    *(uint4*)&Bt[tid * 8] = rb0;  *(uint4*)&Bt[2048 + tid * 8] = rb1;
    __syncthreads();
    if (ks + 1 < ksteps) {
      ra0 = *(const uint4*)(ga + (ks + 1) * 32);
      ra1 = *(const uint4*)(ga + (size_t)64 * K + (ks + 1) * 32);
      rb0 = *(const uint4*)(gb + (ks + 1) * 32);
      rb1 = *(const uint4*)(gb + (size_t)64 * K + (ks + 1) * 32);
    }
    bf16x8 af[4], bfr[4];
#pragma unroll
    for (int i = 0; i < 4; ++i) af[i]  = *(const bf16x8*)&At[(wr + i * 16 + frow) * 32 + fk];
#pragma unroll
    for (int j = 0; j < 4; ++j) bfr[j] = *(const bf16x8*)&Bt[(wc + j * 16 + frow) * 32 + fk];
#pragma unroll
    for (int i = 0; i < 4; ++i)
#pragma unroll
      for (int j = 0; j < 4; ++j)
        acc[i][j] = __builtin_amdgcn_mfma_f32_16x16x32_bf16(af[i], bfr[j], acc[i][j], 0, 0, 0);
  }
  int crow = (lane >> 4) * 4, ccol = lane & 15;
#pragma unroll
  for (int i = 0; i < 4; ++i) {
    int o0 = mt * 128 + wr + i * 16 + crow;
    float s0 = scp[o0], s1 = scp[o0+1], s2 = scp[o0+2], s3 = scp[o0+3];
    float t0 = shp[o0], t1 = shp[o0+1], t2 = shp[o0+2], t3 = shp[o0+3];
#pragma unroll
    for (int j = 0; j < 4; ++j) {
      int bn = ct * 128 + wc + j * 16 + ccol;
      float b0 = 0.f, b1 = 0.f, b2 = 0.f, b3 = 0.f;
      if (bias2) {
        const float* bp = bias2 + (size_t)(bn >> 11) * M + o0;
        b0 = bp[0]; b1 = bp[1]; b2 = bp[2]; b3 = bp[3];
      }
      bf16x4 pk;
      pk[0] = (bf16_t)relu_(fmaf(acc[i][j][0], s0, t0 + b0));
      pk[1] = (bf16_t)relu_(fmaf(acc[i][j][1], s1, t1 + b1));
      pk[2] = (bf16_t)relu_(fmaf(acc[i][j][2], s2, t2 + b2));
      pk[3] = (bf16_t)relu_(fmaf(acc[i][j][3], s3, t3 + b3));
      *(bf16x4*)(Cout + (size_t)bn * M + o0) = pk;
    }
  }
}

// ---------------------------------------------------------------- convs3 (256->16) + bias, fp32 out
__global__ __launch_bounds__(128) void k_gemm3(const bf16_t* __restrict__ g2, const float* __restrict__ w3,
    const float* __restrict__ b3, float* __restrict__ out)
{
  __shared__ float wsT[4096];   // [k][o]
  __shared__ float bb[16];
  int tid = threadIdx.x;
  for (int i = tid; i < 4096; i += 128) { int o = i >> 8, k = i & 255; wsT[k * 16 + o] = w3[i]; }
  if (tid < 16) bb[tid] = b3[tid];
  __syncthreads();
  int col = blockIdx.x * 128 + tid;
  int b = col >> 11, n = col & 2047;
  const bf16_t* g = g2 + (size_t)col * 256;
  float acc[16];
#pragma unroll
  for (int o = 0; o < 16; ++o) acc[o] = 0.f;
  for (int k0 = 0; k0 < 256; k0 += 8) {
    bf16x8 gv8 = *(const bf16x8*)(g + k0);
#pragma unroll
    for (int kk = 0; kk < 8; ++kk) {
      float gv = (float)gv8[kk];
      const float* wr = &wsT[(k0 + kk) * 16];
#pragma unroll
      for (int o = 0; o < 16; ++o) acc[o] = fmaf(wr[o], gv, acc[o]);
    }
  }
  float* op = out + (size_t)b * 16 * 2048 + n;
#pragma unroll
  for (int o = 0; o < 16; ++o) op[(size_t)o * 2048] = acc[o] + bb[o];
}

// ---------------------------------------------------------------- launch
extern "C" void kernel_launch(void* const* d_in, const int* in_sizes, int n_in,
                              void* d_out, int out_size, void* d_ws, size_t ws_size,
                              hipStream_t stream)
{
  const float* x         = (const float*)d_in[0];
  const float* conv1_w   = (const float*)d_in[1];
  const float* bn1       = (const float*)d_in[2];
  const float* conv2_w   = (const float*)d_in[3];
  const float* bn2       = (const float*)d_in[4];
  const float* sa_qk_w   = (const float*)d_in[5];
  const float* sa_v_w    = (const float*)d_in[6];
  const float* sa_v_b    = (const float*)d_in[7];
  const float* sa_trans_w= (const float*)d_in[8];
  const float* sa_trans_b= (const float*)d_in[9];
  const float* sa_bn     = (const float*)d_in[10];
  const float* fuse_w    = (const float*)d_in[11];
  const float* fuse_bn   = (const float*)d_in[12];
  const float* convs1_w  = (const float*)d_in[13];
  const float* convs1_b  = (const float*)d_in[14];
  const float* bns1      = (const float*)d_in[15];
  const float* convs2_w  = (const float*)d_in[16];
  const float* convs2_b  = (const float*)d_in[17];
  const float* bns2      = (const float*)d_in[18];
  const float* convs3_w  = (const float*)d_in[19];
  const float* convs3_b  = (const float*)d_in[20];

  char* ws = (char*)d_ws;
  float*  xqqw  = (float*)(ws + 0);            // 16 MB
  float*  feats = (float*)(ws + 16777216);     // 8 MB
  float*  h0    = (float*)(ws + 25165824);     // 2 MB
  float*  kbuf  = (float*)(ws + 27262976);     // 0.5 MB
  float*  vbuf  = (float*)(ws + 27787264);     // 2 MB
  float*  Lpart = (float*)(ws + 29884416);     // 2 MB
  float*  parts = (float*)(ws + 31981568);     // 8.9 MB
  bf16_t* gbuf  = (bf16_t*)(ws + 42991616);    // 8 MB
  bf16_t* g2    = (bf16_t*)(ws + 51380224);    // 16 MB
  bf16_t* g1    = (bf16_t*)(ws + 0);           // 32 MB, overlays dead attn buffers
  bf16_t* wbuf1 = (bf16_t*)(ws + 68157440);    // 128 KB
  bf16_t* wbuf2 = (bf16_t*)(ws + 68288512);    // 256 KB
  float*  params= (float*)(ws + 68550656);
  float*  xmaxf = (float*)(ws + 68567040);
  float*  xavg  = (float*)(ws + 68575232);
  float*  bias2 = (float*)(ws + 68579328);

  k_prep<<<256, 256, 0, stream>>>(convs1_w, convs2_w, bn1, bn2, sa_bn, sa_trans_b, fuse_bn,
                                  convs1_b, bns1, convs2_b, bns2, wbuf1, wbuf2, params);
  k_convs<<<256, 256, 0, stream>>>(x, conv1_w, conv2_w, params, sa_qk_w, sa_v_w, sa_v_b,
                                   h0, kbuf, vbuf);
  for (int i = 0; i < 4; ++i) {
    k_rowstats<<<1024, 256, 0, stream>>>(kbuf, Lpart);
    k_colaccum<<<512, 256, 0, stream>>>(kbuf, vbuf, Lpart, parts);
    const float* hin = (i == 0) ? h0 : (feats + (size_t)(i - 1) * 16 * 2048);
    int hbs = (i == 0) ? 16 * 2048 : 64 * 2048;
    bool last = (i == 3);
    k_epilogue<<<512, 256, 0, stream>>>(parts, hin, hbs, sa_trans_w + i * 256, params, i,
        feats + (size_t)i * 16 * 2048,
        last ? nullptr : sa_qk_w + (i + 1) * 64,
        last ? nullptr : sa_v_w + (i + 1) * 256,
        last ? nullptr : sa_v_b + (i + 1) * 16,
        kbuf, vbuf);
  }
  k_fuse<<<512, 256, 0, stream>>>(feats, fuse_w, params, xqqw, gbuf);
  k_argmax<<<2048, 256, 0, stream>>>(xqqw, xmaxf, xavg);
  k_bias2<<<32, 256, 0, stream>>>(convs1_w, xmaxf, xavg, params, bias2);
  k_gemm<<<1024, 256, 0, stream>>>(wbuf1, gbuf, params + 672, params + 1184, bias2, g1, 512, 128, 4);
  k_gemm<<<512, 256, 0, stream>>>(wbuf2, g1, params + 1696, params + 1952, nullptr, g2, 256, 512, 2);
  k_gemm3<<<256, 128, 0, stream>>>(g2, convs3_w, convs3_b, (float*)d_out);
}

// Round 3
// 551.888 us; speedup vs baseline: 1.0516x; 1.0227x over previous
//
#include <hip/hip_runtime.h>
#include <stdint.h>

typedef __bf16 bf16_t;
typedef __bf16 bf16x8 __attribute__((ext_vector_type(8)));
typedef __bf16 bf16x4 __attribute__((ext_vector_type(4)));
typedef float f32x4 __attribute__((ext_vector_type(4)));
typedef float f32x2 __attribute__((ext_vector_type(2)));

#define LOG2E 1.4426950408889634f

__device__ __forceinline__ float relu_(float v) { return v > 0.f ? v : 0.f; }

// ---------------------------------------------------------------- prep
// params layout (floats):
// 0 bn1_scale[128] |128 bn1_shift[128] |256 bn2_scale[16] |272 bn2_shift[16]
// 288 sa_scale[64] |352 sa_shift[64] |416 fuse_scale[128] |544 fuse_shift[128]
// 672 bns1_scale[512] |1184 bns1_shift[512] |1696 bns2_scale[256] |1952 bns2_shift[256]
__global__ __launch_bounds__(256) void k_prep(
    const float* __restrict__ convs1_w, const float* __restrict__ convs2_w,
    const float* __restrict__ bn1, const float* __restrict__ bn2,
    const float* __restrict__ sa_bn, const float* __restrict__ sa_trans_b,
    const float* __restrict__ fuse_bn, const float* __restrict__ convs1_b,
    const float* __restrict__ bns1, const float* __restrict__ convs2_b,
    const float* __restrict__ bns2,
    bf16_t* __restrict__ wbuf1, bf16_t* __restrict__ wbuf2, float* __restrict__ params)
{
  int idx = blockIdx.x * 256 + threadIdx.x;
  for (int it = 0; it < 3; ++it) {
    int i = idx + it * 65536;
    if (i < 65536) {                        // wbuf1 [512][128] = first 128 cols of convs1_w
      int o = i >> 7, c = i & 127;
      wbuf1[i] = (bf16_t)convs1_w[o * 264 + c];
    } else if (i < 65536 + 131072) {        // wbuf2 [256][512]
      int j = i - 65536;
      wbuf2[j] = (bf16_t)convs2_w[j];
    }
  }
  if (blockIdx.x == 0) {
    for (int t = threadIdx.x; t < 1104; t += 256) {
      float g, be, m, v, extra = 0.f; int so, ho;
      if (t < 128)      { g=bn1[t]; be=bn1[128+t]; m=bn1[256+t]; v=bn1[384+t]; so=t; ho=128+t; }
      else if (t < 144) { int u=t-128; g=bn2[u]; be=bn2[16+u]; m=bn2[32+u]; v=bn2[48+u]; so=256+u; ho=272+u; }
      else if (t < 208) { int u=t-144; int L=u>>4, o=u&15; const float* p=sa_bn+L*64;
                          g=p[o]; be=p[16+o]; m=p[32+o]; v=p[48+o];
                          extra=sa_trans_b[L*16+o]; so=288+u; ho=352+u; }
      else if (t < 336) { int u=t-208; g=fuse_bn[u]; be=fuse_bn[128+u]; m=fuse_bn[256+u]; v=fuse_bn[384+u]; so=416+u; ho=544+u; }
      else if (t < 848) { int u=t-336; g=bns1[u]; be=bns1[512+u]; m=bns1[1024+u]; v=bns1[1536+u]; extra=convs1_b[u]; so=672+u; ho=1184+u; }
      else              { int u=t-848; g=bns2[u]; be=bns2[256+u]; m=bns2[512+u]; v=bns2[768+u]; extra=convs2_b[u]; so=1696+u; ho=1952+u; }
      float sc = g * rsqrtf(v + 1e-5f);
      params[so] = sc;
      params[ho] = (extra - m) * sc + be;
    }
  }
}

// ---------------------------------------------------------------- fused conv1(16->128)+bn+relu -> conv2(128->16)+bn+relu -> layer0 k/v
__global__ __launch_bounds__(256) void k_convs(const float* __restrict__ x,
    const float* __restrict__ w1, const float* __restrict__ w2,
    const float* __restrict__ params, const float* __restrict__ qk_w,
    const float* __restrict__ v_w, const float* __restrict__ v_b,
    float* __restrict__ h0, float* __restrict__ kbuf, float* __restrict__ vbufT)
{
  __shared__ __align__(16) float xs[16 * 128];
  __shared__ float ws1[128 * 17];
  __shared__ float ws2[16 * 129];
  __shared__ __align__(16) float h1s[128 * 64];
  __shared__ float hcv[128 * 17];
  __shared__ float qk[64], vw[256], vb[16], sc1[128], sh1[128], sc2[16], sh2[16];
  int t = threadIdx.x;
  int bid = blockIdx.x;                       // 256 = b*16 + chunk(128 cols)
  int b = bid >> 4, n0 = (bid & 15) * 128;
  for (int i = t; i < 2048; i += 256) { int c = i >> 7, col = i & 127; xs[c * 128 + col] = x[((size_t)b * 16 + c) * 2048 + n0 + col]; }
  for (int i = t; i < 2048; i += 256) { int o = i >> 4, c = i & 15;  ws1[o * 17 + c]  = w1[i]; }
  for (int i = t; i < 2048; i += 256) { int o = i >> 7, c = i & 127; ws2[o * 129 + c] = w2[i]; }
  if (t < 64) qk[t] = qk_w[t];
  vw[t] = v_w[t];
  if (t < 16) { vb[t] = v_b[t]; sc2[t] = params[256 + t]; sh2[t] = params[272 + t]; }
  if (t < 128) { sc1[t] = params[t]; sh1[t] = params[128 + t]; }
  __syncthreads();
  int colh = t & 63, hi4 = t >> 6;
  int cg = t & 15, og = t >> 4;
  for (int h = 0; h < 2; ++h) {
    int cb = h * 64;
    // phase B: conv1 for 64 cols, all 128 outs
    float xr[16];
#pragma unroll
    for (int c = 0; c < 16; ++c) xr[c] = xs[c * 128 + cb + colh];
#pragma unroll 4
    for (int i = 0; i < 32; ++i) {
      int o = (i << 2) | hi4;
      float s = 0.f;
#pragma unroll
      for (int c = 0; c < 16; ++c) s = fmaf(ws1[o * 17 + c], xr[c], s);
      h1s[o * 64 + colh] = relu_(fmaf(s, sc1[o], sh1[o]));
    }
    __syncthreads();
    // phase C: conv2 (128->16) for the 64 cols
    float a0 = 0.f, a1 = 0.f, a2 = 0.f, a3 = 0.f;
    for (int c = 0; c < 128; ++c) {
      float4 f = *(const float4*)&h1s[c * 64 + cg * 4];
      float w = ws2[og * 129 + c];
      a0 = fmaf(w, f.x, a0); a1 = fmaf(w, f.y, a1);
      a2 = fmaf(w, f.z, a2); a3 = fmaf(w, f.w, a3);
    }
    float4 v4;
    v4.x = relu_(fmaf(a0, sc2[og], sh2[og]));
    v4.y = relu_(fmaf(a1, sc2[og], sh2[og]));
    v4.z = relu_(fmaf(a2, sc2[og], sh2[og]));
    v4.w = relu_(fmaf(a3, sc2[og], sh2[og]));
    *(float4*)&h0[((size_t)b * 16 + og) * 2048 + n0 + cb + cg * 4] = v4;
    hcv[(cb + cg * 4 + 0) * 17 + og] = v4.x;
    hcv[(cb + cg * 4 + 1) * 17 + og] = v4.y;
    hcv[(cb + cg * 4 + 2) * 17 + og] = v4.z;
    hcv[(cb + cg * 4 + 3) * 17 + og] = v4.w;
    __syncthreads();
  }
  // phase D: k (4 outs) + v (16 outs) projections
  int col = t & 127, ug = t >> 7;
  float hr[16];
#pragma unroll
  for (int c = 0; c < 16; ++c) hr[c] = hcv[col * 17 + c];
#pragma unroll
  for (int i = 0; i < 10; ++i) {
    int u = ug * 10 + i;
    const float* W = (u < 4) ? &qk[u * 16] : &vw[(u - 4) * 16];
    float s = (u < 4) ? 0.f : vb[u - 4];
#pragma unroll
    for (int c = 0; c < 16; ++c) s = fmaf(W[c], hr[c], s);
    if (u < 4) kbuf[((size_t)b * 2048 + n0 + col) * 4 + u] = s;
    else       vbufT[((size_t)b * 2048 + n0 + col) * 16 + (u - 4)] = s;
  }
}

// ---------------------------------------------------------------- pass A: row softmax denominators (8 m-splits)
__global__ __launch_bounds__(256) void k_rowstats(const float* __restrict__ kbuf, float* __restrict__ Lpart)
{
  __shared__ float4 kch[256];
  int bid = blockIdx.x;                     // 1024 = b*64 + nt*8 + ms
  int b = bid >> 6, nt = (bid >> 3) & 7, ms = bid & 7;
  int t = threadIdx.x;
  const float4* kb = (const float4*)kbuf + b * 2048;
  kch[t] = kb[ms * 256 + t];
  __syncthreads();
  int n = nt * 256 + t;
  float4 q = kb[n];
  q.x *= LOG2E; q.y *= LOG2E; q.z *= LOG2E; q.w *= LOG2E;
  float L = 0.f;
#pragma unroll 4
  for (int m = 0; m < 256; ++m) {
    float4 k4 = kch[m];
    float s = fmaf(q.x, k4.x, fmaf(q.y, k4.y, fmaf(q.z, k4.z, q.w * k4.w)));
    L += exp2f(s);
  }
  Lpart[((size_t)ms * 16 + b) * 2048 + n] = L;
}

// ---------------------------------------------------------------- pass B: column accumulation (8 n-splits, 2 m per lane)
__global__ __launch_bounds__(256) void k_colaccum(const float* __restrict__ kbuf, const float* __restrict__ vbufT,
    const float* __restrict__ Lpart, float* __restrict__ parts)
{
  __shared__ __align__(16) float ku[256 * 8];
  __shared__ __align__(16) float vch[256 * 16];
  int bid = blockIdx.x;                     // 512 = b*32 + mt*8 + ns
  int b = bid >> 5, mt = (bid >> 3) & 3, ns = bid & 7;
  int t = threadIdx.x;
  // stage 256-n chunk: k4 + lg2(1/L) packed [n][8]; V transposed [n][16]
  {
    int n = ns * 256 + t;
    float4 k4 = ((const float4*)kbuf)[b * 2048 + n];
    float Ls = 0.f;
#pragma unroll
    for (int s = 0; s < 8; ++s) Ls += Lpart[((size_t)s * 16 + b) * 2048 + n];
    *(float4*)&ku[t * 8] = k4;
    ku[t * 8 + 4] = -__log2f(Ls);
    const float4* vp = (const float4*)&vbufT[((size_t)b * 2048 + n) * 16];
    *(float4*)&vch[t * 16 + 0]  = vp[0];
    *(float4*)&vch[t * 16 + 4]  = vp[1];
    *(float4*)&vch[t * 16 + 8]  = vp[2];
    *(float4*)&vch[t * 16 + 12] = vp[3];
  }
  __syncthreads();
  int m0 = mt * 512 + t;
  float4 qa = ((const float4*)kbuf)[b * 2048 + m0];
  float4 qb = ((const float4*)kbuf)[b * 2048 + m0 + 256];
  qa.x *= LOG2E; qa.y *= LOG2E; qa.z *= LOG2E; qa.w *= LOG2E;
  qb.x *= LOG2E; qb.y *= LOG2E; qb.z *= LOG2E; qb.w *= LOG2E;
  f32x2 acc0[8], acc1[8];
#pragma unroll
  for (int j = 0; j < 8; ++j) { acc0[j] = (f32x2){0.f, 0.f}; acc1[j] = (f32x2){0.f, 0.f}; }
  float den0 = 0.f, den1 = 0.f;
#pragma unroll 2
  for (int nn = 0; nn < 256; ++nn) {
    f32x4 k4 = *(const f32x4*)&ku[nn * 8];
    float lg = ku[nn * 8 + 4];
    float s0 = fmaf(qa.x, k4[0], fmaf(qa.y, k4[1], fmaf(qa.z, k4[2], fmaf(qa.w, k4[3], lg))));
    float s1 = fmaf(qb.x, k4[0], fmaf(qb.y, k4[1], fmaf(qb.z, k4[2], fmaf(qb.w, k4[3], lg))));
    float e0 = exp2f(s0), e1 = exp2f(s1);
    den0 += e0; den1 += e1;
    f32x2 ev0 = {e0, e0}, ev1 = {e1, e1};
    const f32x2* vp = (const f32x2*)&vch[nn * 16];
#pragma unroll
    for (int j = 0; j < 8; ++j) { f32x2 v2 = vp[j]; acc0[j] += ev0 * v2; acc1[j] += ev1 * v2; }
  }
  float* p = parts + ((size_t)(ns * 16 + b) * 17) * 2048 + m0;
#pragma unroll
  for (int c = 0; c < 16; ++c) p[(size_t)c * 2048] = acc0[c >> 1][c & 1];
  p[(size_t)16 * 2048] = den0;
  p += 256;
#pragma unroll
  for (int c = 0; c < 16; ++c) p[(size_t)c * 2048] = acc1[c >> 1][c & 1];
  p[(size_t)16 * 2048] = den1;
}

// ---------------------------------------------------------------- SA epilogue: combine + trans/bn/relu + residual (+ next k/v)
__global__ __launch_bounds__(256) void k_epilogue(const float* __restrict__ parts,
    const float* __restrict__ hin, int hbs, const float* __restrict__ t_w,
    const float* __restrict__ params, int layer, float* __restrict__ hout,
    const float* __restrict__ qk_w, const float* __restrict__ v_w, const float* __restrict__ v_b,
    float* __restrict__ kbuf, float* __restrict__ vbufT)
{
  __shared__ float pd[17 * 64];
  __shared__ float hs[16 * 64];
  __shared__ float dl[16 * 64];
  __shared__ float hv[64 * 17];
  __shared__ float tw[256], qk[64], vw[256], vb[16], sc[16], sh[16];
  int t = threadIdx.x;
  int bid = blockIdx.x;                     // 512 = b*32 + chunk(64 cols)
  int b = bid >> 5, n0 = (bid & 31) * 64;
  tw[t] = t_w[t];
  if (qk_w) { if (t < 64) qk[t] = qk_w[t]; vw[t] = v_w[t]; if (t < 16) vb[t] = v_b[t]; }
  if (t < 16) { sc[t] = params[288 + layer * 16 + t]; sh[t] = params[352 + layer * 16 + t]; }
  for (int i = t; i < 1088; i += 256) {
    int r = i >> 6, c = i & 63;
    float s = 0.f;
#pragma unroll
    for (int sp = 0; sp < 8; ++sp)
      s += parts[((size_t)(sp * 16 + b) * 17 + r) * 2048 + n0 + c];
    pd[i] = s;
  }
  for (int i = t; i < 1024; i += 256) {
    int c = i >> 6, col = i & 63;
    hs[i] = hin[(size_t)b * hbs + (size_t)c * 2048 + n0 + col];
  }
  __syncthreads();
  int col = t & 63, g4 = t >> 6;
  float inv = 1.f / (1e-9f + pd[16 * 64 + col]);
#pragma unroll
  for (int j = 0; j < 4; ++j) {
    int c = g4 * 4 + j;
    dl[c * 64 + col] = hs[c * 64 + col] - pd[c * 64 + col] * inv;
  }
  __syncthreads();
#pragma unroll
  for (int j = 0; j < 4; ++j) {
    int o = g4 * 4 + j;
    float y = 0.f;
#pragma unroll
    for (int c = 0; c < 16; ++c) y = fmaf(tw[o * 16 + c], dl[c * 64 + col], y);
    y = relu_(fmaf(y, sc[o], sh[o]));
    float hh = hs[o * 64 + col] + y;
    hout[(size_t)b * 64 * 2048 + (size_t)o * 2048 + n0 + col] = hh;
    hv[col * 17 + o] = hh;
  }
  if (qk_w) {
    __syncthreads();
    float hr[16];
#pragma unroll
    for (int c = 0; c < 16; ++c) hr[c] = hv[col * 17 + c];
#pragma unroll
    for (int i = 0; i < 5; ++i) {
      int u = g4 * 5 + i;
      const float* W = (u < 4) ? &qk[u * 16] : &vw[(u - 4) * 16];
      float s = (u < 4) ? 0.f : vb[u - 4];
#pragma unroll
      for (int c = 0; c < 16; ++c) s = fmaf(W[c], hr[c], s);
      if (u < 4) kbuf[((size_t)b * 2048 + n0 + col) * 4 + u] = s;
      else       vbufT[((size_t)b * 2048 + n0 + col) * 16 + (u - 4)] = s;
    }
  }
}

// ---------------------------------------------------------------- fuse conv (64->128) + bn + leaky relu
__global__ __launch_bounds__(256) void k_fuse(const float* __restrict__ feats, const float* __restrict__ fw,
    const float* __restrict__ params, float* __restrict__ xqqw, bf16_t* __restrict__ gbuf)
{
  __shared__ float ws[128 * 65];
  __shared__ __align__(16) float fst[64 * 64];
  __shared__ float sc[128], sh[128];
  int t = threadIdx.x, bid = blockIdx.x;    // 512 = b*32 + chunk(64 cols)
  int b = bid >> 5, n0 = (bid & 31) * 64;
  for (int i = t; i < 8192; i += 256) { int o = i >> 6, c = i & 63; ws[o * 65 + c] = fw[i]; }
  for (int i = t; i < 4096; i += 256) { int c = i >> 6, col = i & 63; fst[i] = feats[((size_t)b * 64 + c) * 2048 + n0 + col]; }
  if (t < 128) { sc[t] = params[416 + t]; sh[t] = params[544 + t]; }
  __syncthreads();
  int cg = t & 7, og = t >> 3;              // 8 col-grps(8 cols) x 32 out-grps(4 outs)
  f32x2 acc[4][4];
#pragma unroll
  for (int oo = 0; oo < 4; ++oo)
#pragma unroll
    for (int j = 0; j < 4; ++j) acc[oo][j] = (f32x2){0.f, 0.f};
  for (int c = 0; c < 64; ++c) {
    const f32x2* fp = (const f32x2*)&fst[c * 64 + cg * 8];
    f32x2 f0 = fp[0], f1 = fp[1], f2v = fp[2], f3 = fp[3];
#pragma unroll
    for (int oo = 0; oo < 4; ++oo) {
      float w = ws[(og * 4 + oo) * 65 + c];
      f32x2 wv = {w, w};
      acc[oo][0] += wv * f0; acc[oo][1] += wv * f1;
      acc[oo][2] += wv * f2v; acc[oo][3] += wv * f3;
    }
  }
  float y[4][8];
#pragma unroll
  for (int oo = 0; oo < 4; ++oo) {
    int o = og * 4 + oo;
    float s0 = sc[o], s1 = sh[o];
#pragma unroll
    for (int j = 0; j < 8; ++j) {
      float v = fmaf(acc[oo][j >> 1][j & 1], s0, s1);
      y[oo][j] = v > 0.f ? v : 0.2f * v;
    }
    float4 v0 = {y[oo][0], y[oo][1], y[oo][2], y[oo][3]};
    float4 v1 = {y[oo][4], y[oo][5], y[oo][6], y[oo][7]};
    *(float4*)&xqqw[((size_t)b * 128 + o) * 2048 + n0 + cg * 8] = v0;
    *(float4*)&xqqw[((size_t)b * 128 + o) * 2048 + n0 + cg * 8 + 4] = v1;
  }
#pragma unroll
  for (int j = 0; j < 8; ++j) {
    int col = n0 + cg * 8 + j;
    bf16x4 pk;
    pk[0] = (bf16_t)y[0][j]; pk[1] = (bf16_t)y[1][j];
    pk[2] = (bf16_t)y[2][j]; pk[3] = (bf16_t)y[3][j];
    *(bf16x4*)&gbuf[((size_t)b * 2048 + col) * 128 + og * 4] = pk;
  }
}

// ---------------------------------------------------------------- argmax over n (+ batch-1 channel means)
__global__ __launch_bounds__(256) void k_argmax(const float* __restrict__ xqqw,
    float* __restrict__ xmaxf, float* __restrict__ xavg)
{
  __shared__ float sv[256]; __shared__ int si[256]; __shared__ float ss[256];
  int bo = blockIdx.x;                     // b*128+o
  int b = bo >> 7, o = bo & 127;
  const float* row = xqqw + (size_t)bo * 2048;
  int tid = threadIdx.x;
  float best = -3.4e38f; int bi = 0; float sum = 0.f;
#pragma unroll
  for (int j = 0; j < 8; ++j) {
    int n = j * 256 + tid;
    float v = row[n];
    sum += v;
    if (v > best) { best = v; bi = n; }
  }
  sv[tid] = best; si[tid] = bi; ss[tid] = sum;
  __syncthreads();
  for (int s = 128; s > 0; s >>= 1) {
    if (tid < s) {
      float v2 = sv[tid + s]; int i2 = si[tid + s];
      if (v2 > sv[tid] || (v2 == sv[tid] && i2 < si[tid])) { sv[tid] = v2; si[tid] = i2; }
      ss[tid] += ss[tid + s];
    }
    __syncthreads();
  }
  if (tid == 0) {
    xmaxf[bo] = (float)si[0];
    if (b == 1) xavg[o] = ss[0] * (1.0f / 2048.0f);
  }
}

// ---------------------------------------------------------------- exact fp32 bias from x_max/x_avg rows (replaces g rows 128..287)
__global__ __launch_bounds__(256) void k_bias2(const float* __restrict__ w1,
    const float* __restrict__ xmaxf, const float* __restrict__ xavg,
    const float* __restrict__ params, float* __restrict__ bias2)
{
  int id = blockIdx.x * 256 + threadIdx.x;   // 8192 = o*16 + b
  int o = id >> 4, b = id & 15;
  const float* wr = w1 + (size_t)o * 264;
  float s = 0.f;
  for (int u = 0; u < 128; ++u) s = fmaf(wr[128 + u], xmaxf[b * 128 + u], s);
#pragma unroll
  for (int u = 0; u < 8; ++u)  s = fmaf(wr[256 + u], xavg[b * 8 + u], s);
  bias2[b * 512 + o] = s * params[672 + o];
}

// ---------------------------------------------------------------- bf16 MFMA GEMM: Cout[bn][o] = relu(bn(A[o][:].B[bn][:]) + bias2)
__global__ __launch_bounds__(256) void k_gemm(const bf16_t* __restrict__ A, const bf16_t* __restrict__ Bm,
    const float* __restrict__ scp, const float* __restrict__ shp, const float* __restrict__ bias2,
    bf16_t* __restrict__ Cout, int M, int K, int mtiles)
{
  __shared__ bf16_t At[128 * 32];
  __shared__ bf16_t Bt[128 * 32];
  int tid = threadIdx.x;
  int mt = blockIdx.x % mtiles, ct = blockIdx.x / mtiles;
  int srow = tid >> 2, scol = (tid & 3) << 3;
  const bf16_t* ga = A  + (size_t)(mt * 128 + srow) * K + scol;
  const bf16_t* gb = Bm + (size_t)(ct * 128 + srow) * K + scol;
  int lane = tid & 63, wave = tid >> 6;
  int wr = (wave >> 1) * 64, wc = (wave & 1) * 64;
  int frow = lane & 15, fk = (lane >> 4) * 8;
  const f32x4 z4 = {0.f, 0.f, 0.f, 0.f};
  f32x4 acc[4][4];
#pragma unroll
  for (int i = 0; i < 4; ++i)
#pragma unroll
    for (int j = 0; j < 4; ++j) acc[i][j] = z4;
  uint4 ra0 = *(const uint4*)ga, ra1 = *(const uint4*)(ga + (size_t)64 * K);
  uint4 rb0 = *(const uint4*)gb, rb1 = *(const uint4*)(gb + (size_t)64 * K);
  int ksteps = K >> 5;
  for (int ks = 0; ks < ksteps; ++ks) {
    __syncthreads();
    *(uint4*)&At[tid * 8] = ra0;  *(uint4*)&At[2048 + tid * 8] = ra1;
    *(uint4*)&Bt[tid * 8] = rb0;  *(uint4*)&Bt[2048 + tid * 8] = rb1;
    __syncthreads();
    if (ks + 1 < ksteps) {
      ra0 = *(const uint4*)(ga + (ks + 1) * 32);
      ra1 = *(const uint4*)(ga + (size_t)64 * K + (ks + 1) * 32);
      rb0 = *(const uint4*)(gb + (ks + 1) * 32);
      rb1 = *(const uint4*)(gb + (size_t)64 * K + (ks + 1) * 32);
    }
    bf16x8 af[4], bfr[4];
#pragma unroll
    for (int i = 0; i < 4; ++i) af[i]  = *(const bf16x8*)&At[(wr + i * 16 + frow) * 32 + fk];
#pragma unroll
    for (int j = 0; j < 4; ++j) bfr[j] = *(const bf16x8*)&Bt[(wc + j * 16 + frow) * 32 + fk];
#pragma unroll
    for (int i = 0; i < 4; ++i)
#pragma unroll
      for (int j = 0; j < 4; ++j)
        acc[i][j] = __builtin_amdgcn_mfma_f32_16x16x32_bf16(af[i], bfr[j], acc[i][j], 0, 0, 0);
  }
  int crow = (lane >> 4) * 4, ccol = lane & 15;
#pragma unroll
  for (int i = 0; i < 4; ++i) {
    int o0 = mt * 128 + wr + i * 16 + crow;
    float s0 = scp[o0], s1 = scp[o0+1], s2 = scp[o0+2], s3 = scp[o0+3];
    float t0 = shp[o0], t1 = shp[o0+1], t2 = shp[o0+2], t3 = shp[o0+3];
#pragma unroll
    for (int j = 0; j < 4; ++j) {
      int bn = ct * 128 + wc + j * 16 + ccol;
      float b0 = 0.f, b1 = 0.f, b2 = 0.f, b3 = 0.f;
      if (bias2) {
        const float* bp = bias2 + (size_t)(bn >> 11) * M + o0;
        b0 = bp[0]; b1 = bp[1]; b2 = bp[2]; b3 = bp[3];
      }
      bf16x4 pk;
      pk[0] = (bf16_t)relu_(fmaf(acc[i][j][0], s0, t0 + b0));
      pk[1] = (bf16_t)relu_(fmaf(acc[i][j][1], s1, t1 + b1));
      pk[2] = (bf16_t)relu_(fmaf(acc[i][j][2], s2, t2 + b2));
      pk[3] = (bf16_t)relu_(fmaf(acc[i][j][3], s3, t3 + b3));
      *(bf16x4*)(Cout + (size_t)bn * M + o0) = pk;
    }
  }
}

// ---------------------------------------------------------------- convs3 (256->16) + bias, fp32 out
__global__ __launch_bounds__(128) void k_gemm3(const bf16_t* __restrict__ g2, const float* __restrict__ w3,
    const float* __restrict__ b3, float* __restrict__ out)
{
  __shared__ float wsT[4096];   // [k][o]
  __shared__ float bb[16];
  int tid = threadIdx.x;
  for (int i = tid; i < 4096; i += 128) { int o = i >> 8, k = i & 255; wsT[k * 16 + o] = w3[i]; }
  if (tid < 16) bb[tid] = b3[tid];
  __syncthreads();
  int col = blockIdx.x * 128 + tid;
  int b = col >> 11, n = col & 2047;
  const bf16_t* g = g2 + (size_t)col * 256;
  float acc[16];
#pragma unroll
  for (int o = 0; o < 16; ++o) acc[o] = 0.f;
  for (int k0 = 0; k0 < 256; k0 += 8) {
    bf16x8 gv8 = *(const bf16x8*)(g + k0);
#pragma unroll
    for (int kk = 0; kk < 8; ++kk) {
      float gv = (float)gv8[kk];
      const float* wr = &wsT[(k0 + kk) * 16];
#pragma unroll
      for (int o = 0; o < 16; ++o) acc[o] = fmaf(wr[o], gv, acc[o]);
    }
  }
  float* op = out + (size_t)b * 16 * 2048 + n;
#pragma unroll
  for (int o = 0; o < 16; ++o) op[(size_t)o * 2048] = acc[o] + bb[o];
}

// ---------------------------------------------------------------- launch
extern "C" void kernel_launch(void* const* d_in, const int* in_sizes, int n_in,
                              void* d_out, int out_size, void* d_ws, size_t ws_size,
                              hipStream_t stream)
{
  const float* x         = (const float*)d_in[0];
  const float* conv1_w   = (const float*)d_in[1];
  const float* bn1       = (const float*)d_in[2];
  const float* conv2_w   = (const float*)d_in[3];
  const float* bn2       = (const float*)d_in[4];
  const float* sa_qk_w   = (const float*)d_in[5];
  const float* sa_v_w    = (const float*)d_in[6];
  const float* sa_v_b    = (const float*)d_in[7];
  const float* sa_trans_w= (const float*)d_in[8];
  const float* sa_trans_b= (const float*)d_in[9];
  const float* sa_bn     = (const float*)d_in[10];
  const float* fuse_w    = (const float*)d_in[11];
  const float* fuse_bn   = (const float*)d_in[12];
  const float* convs1_w  = (const float*)d_in[13];
  const float* convs1_b  = (const float*)d_in[14];
  const float* bns1      = (const float*)d_in[15];
  const float* convs2_w  = (const float*)d_in[16];
  const float* convs2_b  = (const float*)d_in[17];
  const float* bns2      = (const float*)d_in[18];
  const float* convs3_w  = (const float*)d_in[19];
  const float* convs3_b  = (const float*)d_in[20];

  char* ws = (char*)d_ws;
  float*  xqqw  = (float*)(ws + 0);            // 16 MB
  float*  feats = (float*)(ws + 16777216);     // 8 MB
  float*  h0    = (float*)(ws + 25165824);     // 2 MB
  float*  kbuf  = (float*)(ws + 27262976);     // 0.5 MB
  float*  vbufT = (float*)(ws + 27787264);     // 2 MB
  float*  Lpart = (float*)(ws + 29884416);     // 1 MB
  float*  parts = (float*)(ws + 30932992);     // 17.83 MB  [8][16][17][2048] f32
  bf16_t* gbuf  = (bf16_t*)(ws + 48758784);    // 8 MB
  bf16_t* g2    = (bf16_t*)(ws + 57147392);    // 16 MB
  bf16_t* g1    = (bf16_t*)(ws + 0);           // 32 MB, overlays dead attn buffers
  bf16_t* wbuf1 = (bf16_t*)(ws + 73924608);    // 128 KB
  bf16_t* wbuf2 = (bf16_t*)(ws + 74055680);    // 256 KB
  float*  params= (float*)(ws + 74317824);
  float*  xmaxf = (float*)(ws + 74334208);
  float*  xavg  = (float*)(ws + 74342400);
  float*  bias2 = (float*)(ws + 74346496);

  k_prep<<<256, 256, 0, stream>>>(convs1_w, convs2_w, bn1, bn2, sa_bn, sa_trans_b, fuse_bn,
                                  convs1_b, bns1, convs2_b, bns2, wbuf1, wbuf2, params);
  k_convs<<<256, 256, 0, stream>>>(x, conv1_w, conv2_w, params, sa_qk_w, sa_v_w, sa_v_b,
                                   h0, kbuf, vbufT);
  for (int i = 0; i < 4; ++i) {
    k_rowstats<<<1024, 256, 0, stream>>>(kbuf, Lpart);
    k_colaccum<<<512, 256, 0, stream>>>(kbuf, vbufT, Lpart, parts);
    const float* hin = (i == 0) ? h0 : (feats + (size_t)(i - 1) * 16 * 2048);
    int hbs = (i == 0) ? 16 * 2048 : 64 * 2048;
    bool last = (i == 3);
    k_epilogue<<<512, 256, 0, stream>>>(parts, hin, hbs, sa_trans_w + i * 256, params, i,
        feats + (size_t)i * 16 * 2048,
        last ? nullptr : sa_qk_w + (i + 1) * 64,
        last ? nullptr : sa_v_w + (i + 1) * 256,
        last ? nullptr : sa_v_b + (i + 1) * 16,
        kbuf, vbufT);
  }
  k_fuse<<<512, 256, 0, stream>>>(feats, fuse_w, params, xqqw, gbuf);
  k_argmax<<<2048, 256, 0, stream>>>(xqqw, xmaxf, xavg);
  k_bias2<<<32, 256, 0, stream>>>(convs1_w, xmaxf, xavg, params, bias2);
  k_gemm<<<1024, 256, 0, stream>>>(wbuf1, gbuf, params + 672, params + 1184, bias2, g1, 512, 128, 4);
  k_gemm<<<512, 256, 0, stream>>>(wbuf2, g1, params + 1696, params + 1952, nullptr, g2, 256, 512, 2);
  k_gemm3<<<256, 128, 0, stream>>>(g2, convs3_w, convs3_b, (float*)d_out);
}

// Round 4
// 518.311 us; speedup vs baseline: 1.1197x; 1.0648x over previous
//
#include <hip/hip_runtime.h>
#include <stdint.h>

typedef __bf16 bf16_t;
typedef __bf16 bf16x8 __attribute__((ext_vector_type(8)));
typedef __bf16 bf16x4 __attribute__((ext_vector_type(4)));
typedef float f32x4 __attribute__((ext_vector_type(4)));
typedef float f32x2 __attribute__((ext_vector_type(2)));

#define LOG2E 1.4426950408889634f

__device__ __forceinline__ float relu_(float v) { return v > 0.f ? v : 0.f; }

// ---------------------------------------------------------------- prep
// params layout (floats):
// 0 bn1_scale[128] |128 bn1_shift[128] |256 bn2_scale[16] |272 bn2_shift[16]
// 288 sa_scale[64] |352 sa_shift[64] |416 fuse_scale[128] |544 fuse_shift[128]
// 672 bns1_scale[512] |1184 bns1_shift[512] |1696 bns2_scale[256] |1952 bns2_shift[256]
__global__ __launch_bounds__(256) void k_prep(
    const float* __restrict__ convs1_w, const float* __restrict__ convs2_w,
    const float* __restrict__ bn1, const float* __restrict__ bn2,
    const float* __restrict__ sa_bn, const float* __restrict__ sa_trans_b,
    const float* __restrict__ fuse_bn, const float* __restrict__ convs1_b,
    const float* __restrict__ bns1, const float* __restrict__ convs2_b,
    const float* __restrict__ bns2,
    bf16_t* __restrict__ wbuf1, bf16_t* __restrict__ wbuf2, float* __restrict__ params)
{
  int idx = blockIdx.x * 256 + threadIdx.x;
  for (int it = 0; it < 3; ++it) {
    int i = idx + it * 65536;
    if (i < 65536) {                        // wbuf1 [512][128] = first 128 cols of convs1_w
      int o = i >> 7, c = i & 127;
      wbuf1[i] = (bf16_t)convs1_w[o * 264 + c];
    } else if (i < 65536 + 131072) {        // wbuf2 [256][512]
      int j = i - 65536;
      wbuf2[j] = (bf16_t)convs2_w[j];
    }
  }
  if (blockIdx.x == 0) {
    for (int t = threadIdx.x; t < 1104; t += 256) {
      float g, be, m, v, extra = 0.f; int so, ho;
      if (t < 128)      { g=bn1[t]; be=bn1[128+t]; m=bn1[256+t]; v=bn1[384+t]; so=t; ho=128+t; }
      else if (t < 144) { int u=t-128; g=bn2[u]; be=bn2[16+u]; m=bn2[32+u]; v=bn2[48+u]; so=256+u; ho=272+u; }
      else if (t < 208) { int u=t-144; int L=u>>4, o=u&15; const float* p=sa_bn+L*64;
                          g=p[o]; be=p[16+o]; m=p[32+o]; v=p[48+o];
                          extra=sa_trans_b[L*16+o]; so=288+u; ho=352+u; }
      else if (t < 336) { int u=t-208; g=fuse_bn[u]; be=fuse_bn[128+u]; m=fuse_bn[256+u]; v=fuse_bn[384+u]; so=416+u; ho=544+u; }
      else if (t < 848) { int u=t-336; g=bns1[u]; be=bns1[512+u]; m=bns1[1024+u]; v=bns1[1536+u]; extra=convs1_b[u]; so=672+u; ho=1184+u; }
      else              { int u=t-848; g=bns2[u]; be=bns2[256+u]; m=bns2[512+u]; v=bns2[768+u]; extra=convs2_b[u]; so=1696+u; ho=1952+u; }
      float sc = g * rsqrtf(v + 1e-5f);
      params[so] = sc;
      params[ho] = (extra - m) * sc + be;
    }
  }
}

// ---------------------------------------------------------------- fused conv1(16->128)+bn+relu -> conv2(128->16)+bn+relu -> layer0 k/v
__global__ __launch_bounds__(256) void k_convs(const float* __restrict__ x,
    const float* __restrict__ w1, const float* __restrict__ w2,
    const float* __restrict__ params, const float* __restrict__ qk_w,
    const float* __restrict__ v_w, const float* __restrict__ v_b,
    float* __restrict__ h0, float* __restrict__ kbuf, float* __restrict__ vbufT)
{
  __shared__ float xs[16 * 64];
  __shared__ float ws1[128 * 17];
  __shared__ float ws2[16 * 129];
  __shared__ __align__(16) float h1s[128 * 64];
  __shared__ float hcv[64 * 17];
  __shared__ float qk[64], vw[256], vb[16], sc1[128], sh1[128], sc2[16], sh2[16];
  int t = threadIdx.x;
  int bid = blockIdx.x;                       // 512 = b*32 + chunk(64 cols)
  int b = bid >> 5, n0 = (bid & 31) * 64;
  for (int i = t; i < 1024; i += 256) { int c = i >> 6, col = i & 63; xs[i] = x[((size_t)b * 16 + c) * 2048 + n0 + col]; }
  for (int i = t; i < 2048; i += 256) { int o = i >> 4, c = i & 15;  ws1[o * 17 + c]  = w1[i]; }
  for (int i = t; i < 2048; i += 256) { int o = i >> 7, c = i & 127; ws2[o * 129 + c] = w2[i]; }
  if (t < 64) qk[t] = qk_w[t];
  vw[t] = v_w[t];
  if (t < 16) { vb[t] = v_b[t]; sc2[t] = params[256 + t]; sh2[t] = params[272 + t]; }
  if (t < 128) { sc1[t] = params[t]; sh1[t] = params[128 + t]; }
  __syncthreads();
  int col = t & 63, og = t >> 6;
  // conv1: each thread 32 outs for its col
  float xr[16];
#pragma unroll
  for (int c = 0; c < 16; ++c) xr[c] = xs[c * 64 + col];
#pragma unroll 4
  for (int i = 0; i < 32; ++i) {
    int o = og * 32 + i;
    float s = 0.f;
#pragma unroll
    for (int c = 0; c < 16; ++c) s = fmaf(ws1[o * 17 + c], xr[c], s);
    h1s[o * 64 + col] = relu_(fmaf(s, sc1[o], sh1[o]));
  }
  __syncthreads();
  // conv2: each thread 4 outs
  float a[4] = {0.f, 0.f, 0.f, 0.f};
  for (int c = 0; c < 128; ++c) {
    float hv = h1s[c * 64 + col];
#pragma unroll
    for (int oo = 0; oo < 4; ++oo) a[oo] = fmaf(ws2[(og * 4 + oo) * 129 + c], hv, a[oo]);
  }
#pragma unroll
  for (int oo = 0; oo < 4; ++oo) {
    int o = og * 4 + oo;
    float v = relu_(fmaf(a[oo], sc2[o], sh2[o]));
    h0[((size_t)b * 16 + o) * 2048 + n0 + col] = v;
    hcv[col * 17 + o] = v;
  }
  __syncthreads();
  // kv projections: 20 outputs split 5 per og
  float hr[16];
#pragma unroll
  for (int c = 0; c < 16; ++c) hr[c] = hcv[col * 17 + c];
#pragma unroll
  for (int i = 0; i < 5; ++i) {
    int u = og * 5 + i;
    const float* W = (u < 4) ? &qk[u * 16] : &vw[(u - 4) * 16];
    float s = (u < 4) ? 0.f : vb[u - 4];
#pragma unroll
    for (int c = 0; c < 16; ++c) s = fmaf(W[c], hr[c], s);
    if (u < 4) kbuf[((size_t)b * 2048 + n0 + col) * 4 + u] = s;
    else       vbufT[((size_t)b * 2048 + n0 + col) * 16 + (u - 4)] = s;
  }
}

// ---------------------------------------------------------------- pass A: row softmax denominators (16 m-splits)
__global__ __launch_bounds__(256) void k_rowstats(const float* __restrict__ kbuf, float* __restrict__ Lpart)
{
  __shared__ float4 kch[128];
  int bid = blockIdx.x;                     // 2048 = b*128 + nt*16 + ms
  int b = bid >> 7, nt = (bid >> 4) & 7, ms = bid & 15;
  int t = threadIdx.x;
  const float4* kb = (const float4*)kbuf + b * 2048;
  if (t < 128) kch[t] = kb[ms * 128 + t];
  __syncthreads();
  int n = nt * 256 + t;
  float4 q = kb[n];
  q.x *= LOG2E; q.y *= LOG2E; q.z *= LOG2E; q.w *= LOG2E;
  float L = 0.f;
#pragma unroll 4
  for (int m = 0; m < 128; ++m) {
    float4 k4 = kch[m];
    float s = fmaf(q.x, k4.x, fmaf(q.y, k4.y, fmaf(q.z, k4.z, q.w * k4.w)));
    L += exp2f(s);
  }
  Lpart[((size_t)ms * 16 + b) * 2048 + n] = L;
}

// ---------------------------------------------------------------- pass B: column accumulation (16 n-splits, 2 m per lane)
__global__ __launch_bounds__(256) void k_colaccum(const float* __restrict__ kbuf, const float* __restrict__ vbufT,
    const float* __restrict__ Lpart, float* __restrict__ parts)
{
  __shared__ __align__(16) float ku[128 * 8];
  __shared__ __align__(16) float vch[128 * 16];
  int bid = blockIdx.x;                     // 1024 = b*64 + mt*16 + ns
  int b = bid >> 6, mt = (bid >> 4) & 3, ns = bid & 15;
  int t = threadIdx.x;
  // stage 128-n chunk: threads 0-127 -> k4 + lg2(1/L); threads 128-255 -> V[16]
  if (t < 128) {
    int n = ns * 128 + t;
    float4 k4 = ((const float4*)kbuf)[b * 2048 + n];
    float Ls = 0.f;
#pragma unroll
    for (int s = 0; s < 16; ++s) Ls += Lpart[((size_t)s * 16 + b) * 2048 + n];
    *(float4*)&ku[t * 8] = k4;
    ku[t * 8 + 4] = -__log2f(Ls);
  } else {
    int s = t - 128;
    int n = ns * 128 + s;
    const float4* vp = (const float4*)&vbufT[((size_t)b * 2048 + n) * 16];
    *(float4*)&vch[s * 16 + 0]  = vp[0];
    *(float4*)&vch[s * 16 + 4]  = vp[1];
    *(float4*)&vch[s * 16 + 8]  = vp[2];
    *(float4*)&vch[s * 16 + 12] = vp[3];
  }
  __syncthreads();
  int m0 = mt * 512 + t;
  float4 qa = ((const float4*)kbuf)[b * 2048 + m0];
  float4 qb = ((const float4*)kbuf)[b * 2048 + m0 + 256];
  qa.x *= LOG2E; qa.y *= LOG2E; qa.z *= LOG2E; qa.w *= LOG2E;
  qb.x *= LOG2E; qb.y *= LOG2E; qb.z *= LOG2E; qb.w *= LOG2E;
  f32x2 acc0[8], acc1[8];
#pragma unroll
  for (int j = 0; j < 8; ++j) { acc0[j] = (f32x2){0.f, 0.f}; acc1[j] = (f32x2){0.f, 0.f}; }
  float den0 = 0.f, den1 = 0.f;
#pragma unroll 2
  for (int nn = 0; nn < 128; ++nn) {
    f32x4 k4 = *(const f32x4*)&ku[nn * 8];
    float lg = ku[nn * 8 + 4];
    float s0 = fmaf(qa.x, k4[0], fmaf(qa.y, k4[1], fmaf(qa.z, k4[2], fmaf(qa.w, k4[3], lg))));
    float s1 = fmaf(qb.x, k4[0], fmaf(qb.y, k4[1], fmaf(qb.z, k4[2], fmaf(qb.w, k4[3], lg))));
    float e0 = exp2f(s0), e1 = exp2f(s1);
    den0 += e0; den1 += e1;
    f32x4 va = *(const f32x4*)&vch[nn * 16 + 0];
    f32x4 vbb = *(const f32x4*)&vch[nn * 16 + 4];
    f32x4 vc = *(const f32x4*)&vch[nn * 16 + 8];
    f32x4 vd = *(const f32x4*)&vch[nn * 16 + 12];
    f32x2 ev0 = {e0, e0}, ev1 = {e1, e1};
    f32x2 p0 = {va[0], va[1]},  p1 = {va[2], va[3]};
    f32x2 p2 = {vbb[0], vbb[1]}, p3 = {vbb[2], vbb[3]};
    f32x2 p4 = {vc[0], vc[1]},  p5 = {vc[2], vc[3]};
    f32x2 p6 = {vd[0], vd[1]},  p7 = {vd[2], vd[3]};
    acc0[0] += ev0 * p0; acc0[1] += ev0 * p1; acc0[2] += ev0 * p2; acc0[3] += ev0 * p3;
    acc0[4] += ev0 * p4; acc0[5] += ev0 * p5; acc0[6] += ev0 * p6; acc0[7] += ev0 * p7;
    acc1[0] += ev1 * p0; acc1[1] += ev1 * p1; acc1[2] += ev1 * p2; acc1[3] += ev1 * p3;
    acc1[4] += ev1 * p4; acc1[5] += ev1 * p5; acc1[6] += ev1 * p6; acc1[7] += ev1 * p7;
  }
  float* p = parts + ((size_t)(ns * 16 + b) * 17) * 2048 + m0;
#pragma unroll
  for (int c = 0; c < 16; ++c) p[(size_t)c * 2048] = acc0[c >> 1][c & 1];
  p[(size_t)16 * 2048] = den0;
  p += 256;
#pragma unroll
  for (int c = 0; c < 16; ++c) p[(size_t)c * 2048] = acc1[c >> 1][c & 1];
  p[(size_t)16 * 2048] = den1;
}

// ---------------------------------------------------------------- SA epilogue: combine + trans/bn/relu + residual (+ next k/v)
__global__ __launch_bounds__(256) void k_epilogue(const float* __restrict__ parts,
    const float* __restrict__ hin, int hbs, const float* __restrict__ t_w,
    const float* __restrict__ params, int layer, float* __restrict__ hout,
    const float* __restrict__ qk_w, const float* __restrict__ v_w, const float* __restrict__ v_b,
    float* __restrict__ kbuf, float* __restrict__ vbufT)
{
  __shared__ __align__(16) float pd[17 * 64];
  __shared__ float hs[16 * 64];
  __shared__ float dl[16 * 64];
  __shared__ float hv[64 * 17];
  __shared__ float tw[256], qk[64], vw[256], vb[16], sc[16], sh[16];
  int t = threadIdx.x;
  int bid = blockIdx.x;                     // 512 = b*32 + chunk(64 cols)
  int b = bid >> 5, n0 = (bid & 31) * 64;
  tw[t] = t_w[t];
  if (qk_w) { if (t < 64) qk[t] = qk_w[t]; vw[t] = v_w[t]; if (t < 16) vb[t] = v_b[t]; }
  if (t < 16) { sc[t] = params[288 + layer * 16 + t]; sh[t] = params[352 + layer * 16 + t]; }
  // combine 16 partial splits, float4-wide
  for (int i = t; i < 272; i += 256) {
    int r = i >> 4, c4 = (i & 15) << 2;
    f32x4 s = {0.f, 0.f, 0.f, 0.f};
#pragma unroll
    for (int sp = 0; sp < 16; ++sp)
      s += *(const f32x4*)&parts[((size_t)(sp * 16 + b) * 17 + r) * 2048 + n0 + c4];
    *(f32x4*)&pd[r * 64 + c4] = s;
  }
  for (int i = t; i < 1024; i += 256) {
    int c = i >> 6, col = i & 63;
    hs[i] = hin[(size_t)b * hbs + (size_t)c * 2048 + n0 + col];
  }
  __syncthreads();
  int col = t & 63, g4 = t >> 6;
  float inv = 1.f / (1e-9f + pd[16 * 64 + col]);
#pragma unroll
  for (int j = 0; j < 4; ++j) {
    int c = g4 * 4 + j;
    dl[c * 64 + col] = hs[c * 64 + col] - pd[c * 64 + col] * inv;
  }
  __syncthreads();
#pragma unroll
  for (int j = 0; j < 4; ++j) {
    int o = g4 * 4 + j;
    float y = 0.f;
#pragma unroll
    for (int c = 0; c < 16; ++c) y = fmaf(tw[o * 16 + c], dl[c * 64 + col], y);
    y = relu_(fmaf(y, sc[o], sh[o]));
    float hh = hs[o * 64 + col] + y;
    hout[(size_t)b * 64 * 2048 + (size_t)o * 2048 + n0 + col] = hh;
    hv[col * 17 + o] = hh;
  }
  if (qk_w) {
    __syncthreads();
    float hr[16];
#pragma unroll
    for (int c = 0; c < 16; ++c) hr[c] = hv[col * 17 + c];
#pragma unroll
    for (int i = 0; i < 5; ++i) {
      int u = g4 * 5 + i;
      const float* W = (u < 4) ? &qk[u * 16] : &vw[(u - 4) * 16];
      float s = (u < 4) ? 0.f : vb[u - 4];
#pragma unroll
      for (int c = 0; c < 16; ++c) s = fmaf(W[c], hr[c], s);
      if (u < 4) kbuf[((size_t)b * 2048 + n0 + col) * 4 + u] = s;
      else       vbufT[((size_t)b * 2048 + n0 + col) * 16 + (u - 4)] = s;
    }
  }
}

// ---------------------------------------------------------------- fuse conv (64->128) + bn + leaky relu
__global__ __launch_bounds__(256) void k_fuse(const float* __restrict__ feats, const float* __restrict__ fw,
    const float* __restrict__ params, float* __restrict__ xqqw, bf16_t* __restrict__ gbuf)
{
  __shared__ float ws[128 * 65];
  __shared__ __align__(16) float fst[64 * 64];
  __shared__ float sc[128], sh[128];
  int t = threadIdx.x, bid = blockIdx.x;    // 512 = b*32 + chunk(64 cols)
  int b = bid >> 5, n0 = (bid & 31) * 64;
  for (int i = t; i < 8192; i += 256) { int o = i >> 6, c = i & 63; ws[o * 65 + c] = fw[i]; }
  for (int i = t; i < 4096; i += 256) { int c = i >> 6, col = i & 63; fst[i] = feats[((size_t)b * 64 + c) * 2048 + n0 + col]; }
  if (t < 128) { sc[t] = params[416 + t]; sh[t] = params[544 + t]; }
  __syncthreads();
  int cg = t & 7, og = t >> 3;              // 8 col-grps(8 cols) x 32 out-grps(4 outs)
  f32x2 acc[4][4];
#pragma unroll
  for (int oo = 0; oo < 4; ++oo)
#pragma unroll
    for (int j = 0; j < 4; ++j) acc[oo][j] = (f32x2){0.f, 0.f};
  for (int c = 0; c < 64; ++c) {
    const f32x2* fp = (const f32x2*)&fst[c * 64 + cg * 8];
    f32x2 f0 = fp[0], f1 = fp[1], f2v = fp[2], f3 = fp[3];
#pragma unroll
    for (int oo = 0; oo < 4; ++oo) {
      float w = ws[(og * 4 + oo) * 65 + c];
      f32x2 wv = {w, w};
      acc[oo][0] += wv * f0; acc[oo][1] += wv * f1;
      acc[oo][2] += wv * f2v; acc[oo][3] += wv * f3;
    }
  }
  float y[4][8];
#pragma unroll
  for (int oo = 0; oo < 4; ++oo) {
    int o = og * 4 + oo;
    float s0 = sc[o], s1 = sh[o];
#pragma unroll
    for (int j = 0; j < 8; ++j) {
      float v = fmaf(acc[oo][j >> 1][j & 1], s0, s1);
      y[oo][j] = v > 0.f ? v : 0.2f * v;
    }
    float4 v0 = {y[oo][0], y[oo][1], y[oo][2], y[oo][3]};
    float4 v1 = {y[oo][4], y[oo][5], y[oo][6], y[oo][7]};
    *(float4*)&xqqw[((size_t)b * 128 + o) * 2048 + n0 + cg * 8] = v0;
    *(float4*)&xqqw[((size_t)b * 128 + o) * 2048 + n0 + cg * 8 + 4] = v1;
  }
#pragma unroll
  for (int j = 0; j < 8; ++j) {
    int col = n0 + cg * 8 + j;
    bf16x4 pk;
    pk[0] = (bf16_t)y[0][j]; pk[1] = (bf16_t)y[1][j];
    pk[2] = (bf16_t)y[2][j]; pk[3] = (bf16_t)y[3][j];
    *(bf16x4*)&gbuf[((size_t)b * 2048 + col) * 128 + og * 4] = pk;
  }
}

// ---------------------------------------------------------------- argmax over n (+ batch-1 channel means)
__global__ __launch_bounds__(256) void k_argmax(const float* __restrict__ xqqw,
    float* __restrict__ xmaxf, float* __restrict__ xavg)
{
  __shared__ float sv[256]; __shared__ int si[256]; __shared__ float ss[256];
  int bo = blockIdx.x;                     // b*128+o
  int b = bo >> 7, o = bo & 127;
  const float* row = xqqw + (size_t)bo * 2048;
  int tid = threadIdx.x;
  float best = -3.4e38f; int bi = 0; float sum = 0.f;
#pragma unroll
  for (int j = 0; j < 8; ++j) {
    int n = j * 256 + tid;
    float v = row[n];
    sum += v;
    if (v > best) { best = v; bi = n; }
  }
  sv[tid] = best; si[tid] = bi; ss[tid] = sum;
  __syncthreads();
  for (int s = 128; s > 0; s >>= 1) {
    if (tid < s) {
      float v2 = sv[tid + s]; int i2 = si[tid + s];
      if (v2 > sv[tid] || (v2 == sv[tid] && i2 < si[tid])) { sv[tid] = v2; si[tid] = i2; }
      ss[tid] += ss[tid + s];
    }
    __syncthreads();
  }
  if (tid == 0) {
    xmaxf[bo] = (float)si[0];
    if (b == 1) xavg[o] = ss[0] * (1.0f / 2048.0f);
  }
}

// ---------------------------------------------------------------- exact fp32 bias from x_max/x_avg rows (replaces g rows 128..287)
__global__ __launch_bounds__(256) void k_bias2(const float* __restrict__ w1,
    const float* __restrict__ xmaxf, const float* __restrict__ xavg,
    const float* __restrict__ params, float* __restrict__ bias2)
{
  int id = blockIdx.x * 256 + threadIdx.x;   // 8192 = o*16 + b
  int o = id >> 4, b = id & 15;
  const float* wr = w1 + (size_t)o * 264;
  float s = 0.f;
  for (int u = 0; u < 128; ++u) s = fmaf(wr[128 + u], xmaxf[b * 128 + u], s);
#pragma unroll
  for (int u = 0; u < 8; ++u)  s = fmaf(wr[256 + u], xavg[b * 8 + u], s);
  bias2[b * 512 + o] = s * params[672 + o];
}

// ---------------------------------------------------------------- bf16 MFMA GEMM: Cout[bn][o] = relu(bn(A[o][:].B[bn][:]) + bias2)
__global__ __launch_bounds__(256) void k_gemm(const bf16_t* __restrict__ A, const bf16_t* __restrict__ Bm,
    const float* __restrict__ scp, const float* __restrict__ shp, const float* __restrict__ bias2,
    bf16_t* __restrict__ Cout, int M, int K, int mtiles)
{
  __shared__ bf16_t At[128 * 32];
  __shared__ bf16_t Bt[128 * 32];
  int tid = threadIdx.x;
  int mt = blockIdx.x % mtiles, ct = blockIdx.x / mtiles;
  int srow = tid >> 2, scol = (tid & 3) << 3;
  const bf16_t* ga = A  + (size_t)(mt * 128 + srow) * K + scol;
  const bf16_t* gb = Bm + (size_t)(ct * 128 + srow) * K + scol;
  int lane = tid & 63, wave = tid >> 6;
  int wr = (wave >> 1) * 64, wc = (wave & 1) * 64;
  int frow = lane & 15, fk = (lane >> 4) * 8;
  const f32x4 z4 = {0.f, 0.f, 0.f, 0.f};
  f32x4 acc[4][4];
#pragma unroll
  for (int i = 0; i < 4; ++i)
#pragma unroll
    for (int j = 0; j < 4; ++j) acc[i][j] = z4;
  uint4 ra0 = *(const uint4*)ga, ra1 = *(const uint4*)(ga + (size_t)64 * K);
  uint4 rb0 = *(const uint4*)gb, rb1 = *(const uint4*)(gb + (size_t)64 * K);
  int ksteps = K >> 5;
  for (int ks = 0; ks < ksteps; ++ks) {
    __syncthreads();
    *(uint4*)&At[tid * 8] = ra0;  *(uint4*)&At[2048 + tid * 8] = ra1;
    *(uint4*)&Bt[tid * 8] = rb0;  *(uint4*)&Bt[2048 + tid * 8] = rb1;
    __syncthreads();
    if (ks + 1 < ksteps) {
      ra0 = *(const uint4*)(ga + (ks + 1) * 32);
      ra1 = *(const uint4*)(ga + (size_t)64 * K + (ks + 1) * 32);
      rb0 = *(const uint4*)(gb + (ks + 1) * 32);
      rb1 = *(const uint4*)(gb + (size_t)64 * K + (ks + 1) * 32);
    }
    bf16x8 af[4], bfr[4];
#pragma unroll
    for (int i = 0; i < 4; ++i) af[i]  = *(const bf16x8*)&At[(wr + i * 16 + frow) * 32 + fk];
#pragma unroll
    for (int j = 0; j < 4; ++j) bfr[j] = *(const bf16x8*)&Bt[(wc + j * 16 + frow) * 32 + fk];
#pragma unroll
    for (int i = 0; i < 4; ++i)
#pragma unroll
      for (int j = 0; j < 4; ++j)
        acc[i][j] = __builtin_amdgcn_mfma_f32_16x16x32_bf16(af[i], bfr[j], acc[i][j], 0, 0, 0);
  }
  int crow = (lane >> 4) * 4, ccol = lane & 15;
#pragma unroll
  for (int i = 0; i < 4; ++i) {
    int o0 = mt * 128 + wr + i * 16 + crow;
    float s0 = scp[o0], s1 = scp[o0+1], s2 = scp[o0+2], s3 = scp[o0+3];
    float t0 = shp[o0], t1 = shp[o0+1], t2 = shp[o0+2], t3 = shp[o0+3];
#pragma unroll
    for (int j = 0; j < 4; ++j) {
      int bn = ct * 128 + wc + j * 16 + ccol;
      float b0 = 0.f, b1 = 0.f, b2 = 0.f, b3 = 0.f;
      if (bias2) {
        const float* bp = bias2 + (size_t)(bn >> 11) * M + o0;
        b0 = bp[0]; b1 = bp[1]; b2 = bp[2]; b3 = bp[3];
      }
      bf16x4 pk;
      pk[0] = (bf16_t)relu_(fmaf(acc[i][j][0], s0, t0 + b0));
      pk[1] = (bf16_t)relu_(fmaf(acc[i][j][1], s1, t1 + b1));
      pk[2] = (bf16_t)relu_(fmaf(acc[i][j][2], s2, t2 + b2));
      pk[3] = (bf16_t)relu_(fmaf(acc[i][j][3], s3, t3 + b3));
      *(bf16x4*)(Cout + (size_t)bn * M + o0) = pk;
    }
  }
}

// ---------------------------------------------------------------- convs3 (256->16) + bias, fp32 out
__global__ __launch_bounds__(256) void k_gemm3(const bf16_t* __restrict__ g2, const float* __restrict__ w3,
    const float* __restrict__ b3, float* __restrict__ out)
{
  __shared__ float wsT[4096];   // [k][o]
  __shared__ float bb[16];
  int t = threadIdx.x;
  for (int i = t; i < 4096; i += 256) { int o = i >> 8, k = i & 255; wsT[k * 16 + o] = w3[i]; }
  if (t < 16) bb[t] = b3[t];
  __syncthreads();
  int col = blockIdx.x * 64 + (t & 63);     // grid 512
  int og = t >> 6;
  int b = col >> 11, n = col & 2047;
  const bf16_t* g = g2 + (size_t)col * 256;
  float acc[4] = {0.f, 0.f, 0.f, 0.f};
  for (int k0 = 0; k0 < 256; k0 += 8) {
    bf16x8 gv8 = *(const bf16x8*)(g + k0);
#pragma unroll
    for (int kk = 0; kk < 8; ++kk) {
      float gv = (float)gv8[kk];
      const float* wr = &wsT[(k0 + kk) * 16 + og * 4];
#pragma unroll
      for (int oo = 0; oo < 4; ++oo) acc[oo] = fmaf(wr[oo], gv, acc[oo]);
    }
  }
  float* op = out + (size_t)b * 16 * 2048 + n;
#pragma unroll
  for (int oo = 0; oo < 4; ++oo) {
    int o = og * 4 + oo;
    op[(size_t)o * 2048] = acc[oo] + bb[o];
  }
}

// ---------------------------------------------------------------- launch
extern "C" void kernel_launch(void* const* d_in, const int* in_sizes, int n_in,
                              void* d_out, int out_size, void* d_ws, size_t ws_size,
                              hipStream_t stream)
{
  const float* x         = (const float*)d_in[0];
  const float* conv1_w   = (const float*)d_in[1];
  const float* bn1       = (const float*)d_in[2];
  const float* conv2_w   = (const float*)d_in[3];
  const float* bn2       = (const float*)d_in[4];
  const float* sa_qk_w   = (const float*)d_in[5];
  const float* sa_v_w    = (const float*)d_in[6];
  const float* sa_v_b    = (const float*)d_in[7];
  const float* sa_trans_w= (const float*)d_in[8];
  const float* sa_trans_b= (const float*)d_in[9];
  const float* sa_bn     = (const float*)d_in[10];
  const float* fuse_w    = (const float*)d_in[11];
  const float* fuse_bn   = (const float*)d_in[12];
  const float* convs1_w  = (const float*)d_in[13];
  const float* convs1_b  = (const float*)d_in[14];
  const float* bns1      = (const float*)d_in[15];
  const float* convs2_w  = (const float*)d_in[16];
  const float* convs2_b  = (const float*)d_in[17];
  const float* bns2      = (const float*)d_in[18];
  const float* convs3_w  = (const float*)d_in[19];
  const float* convs3_b  = (const float*)d_in[20];

  char* ws = (char*)d_ws;
  float*  xqqw  = (float*)(ws + 0);            // 16 MB
  float*  feats = (float*)(ws + 16777216);     // 8 MB
  float*  h0    = (float*)(ws + 25165824);     // 2 MB
  float*  kbuf  = (float*)(ws + 27262976);     // 0.5 MB
  float*  vbufT = (float*)(ws + 27787264);     // 2 MB
  float*  Lpart = (float*)(ws + 29884416);     // 2 MB  [16][16][2048]
  float*  parts = (float*)(ws + 31981568);     // 35.65 MB  [16][16][17][2048] f32
  bf16_t* g1    = (bf16_t*)(ws + 0);           // 32 MB, overlays xqqw/feats/h0/attn (dead)
  bf16_t* g2    = (bf16_t*)(ws + 33554432);    // 16 MB, overlays parts (dead)
  bf16_t* gbuf  = (bf16_t*)(ws + 50331648);    // 8 MB, overlays parts tail (dead)
  bf16_t* wbuf1 = (bf16_t*)(ws + 67633152);    // 128 KB
  bf16_t* wbuf2 = (bf16_t*)(ws + 67764224);    // 256 KB
  float*  params= (float*)(ws + 68026368);
  float*  xmaxf = (float*)(ws + 68042752);
  float*  xavg  = (float*)(ws + 68050944);
  float*  bias2 = (float*)(ws + 68055040);

  k_prep<<<256, 256, 0, stream>>>(convs1_w, convs2_w, bn1, bn2, sa_bn, sa_trans_b, fuse_bn,
                                  convs1_b, bns1, convs2_b, bns2, wbuf1, wbuf2, params);
  k_convs<<<512, 256, 0, stream>>>(x, conv1_w, conv2_w, params, sa_qk_w, sa_v_w, sa_v_b,
                                   h0, kbuf, vbufT);
  for (int i = 0; i < 4; ++i) {
    k_rowstats<<<2048, 256, 0, stream>>>(kbuf, Lpart);
    k_colaccum<<<1024, 256, 0, stream>>>(kbuf, vbufT, Lpart, parts);
    const float* hin = (i == 0) ? h0 : (feats + (size_t)(i - 1) * 16 * 2048);
    int hbs = (i == 0) ? 16 * 2048 : 64 * 2048;
    bool last = (i == 3);
    k_epilogue<<<512, 256, 0, stream>>>(parts, hin, hbs, sa_trans_w + i * 256, params, i,
        feats + (size_t)i * 16 * 2048,
        last ? nullptr : sa_qk_w + (i + 1) * 64,
        last ? nullptr : sa_v_w + (i + 1) * 256,
        last ? nullptr : sa_v_b + (i + 1) * 16,
        kbuf, vbufT);
  }
  k_fuse<<<512, 256, 0, stream>>>(feats, fuse_w, params, xqqw, gbuf);
  k_argmax<<<2048, 256, 0, stream>>>(xqqw, xmaxf, xavg);
  k_bias2<<<32, 256, 0, stream>>>(convs1_w, xmaxf, xavg, params, bias2);
  k_gemm<<<1024, 256, 0, stream>>>(wbuf1, gbuf, params + 672, params + 1184, bias2, g1, 512, 128, 4);
  k_gemm<<<512, 256, 0, stream>>>(wbuf2, g1, params + 1696, params + 1952, nullptr, g2, 256, 512, 2);
  k_gemm3<<<512, 256, 0, stream>>>(g2, convs3_w, convs3_b, (float*)d_out);
}